// Round 14
// baseline (112.671 us; speedup 1.0000x reference)
//
#include <hip/hip_runtime.h>
#include <math.h>

#define TPB 256

static constexpr int LL = 16;
static constexpr int KK = 2048;
static constexpr int NBATCH = 4;
static constexpr int NN = 4096;        // K*B
static constexpr int BBR = 8;          // (branch, batch) combos

// workspace layout in float slots (ws is ~268MB)
static constexpr size_t OFF_EHL = 0;          // 8*4096*32 bf16 = 524288 f
static constexpr size_t OFF_ET  = 524288;     // 8*16*4096 bf16 = 262144 f (n-permuted)
static constexpr size_t OFF_EAT = 819200;     // 8*2*16*2048 bf16 = 262144 f
static constexpr size_t OFF_PB  = 2129920;    // 2*8*16*4096 f32 = 1048576 f
static constexpr size_t OFF_PMX = 3178496;    // 2*8*4096 f32 = 65536 f
static constexpr size_t OFF_PSM = 3244032;    // 65536 f
static constexpr size_t OFF_PMM = 3309568;    // 4ks*2br*4b*2t*16l*2048j f32 = 2097152 f

typedef unsigned short ushortT;
typedef __attribute__((ext_vector_type(8))) short short8v;
typedef __attribute__((ext_vector_type(4))) float f32x4;
typedef __attribute__((ext_vector_type(16))) float f32x16;

__device__ __forceinline__ ushortT f2bf(float x) {
  union { float f; unsigned int u; } c; c.f = x;
  unsigned int u = c.u;
  return (ushortT)((u + 0x7FFFu + ((u >> 16) & 1u)) >> 16);
}
__device__ __forceinline__ float bf2f(ushortT h) {
  union { unsigned int u; float f; } c; c.u = ((unsigned int)h) << 16;
  return c.f;
}
__device__ __forceinline__ float exp2a(float x) {
  float r; asm("v_exp_f32 %0, %1" : "=v"(r) : "v"(x)); return r;
}

// ---------------------------------------------------------------- prep
// (R8-proven, verbatim.) One branch per blockIdx.z.
__global__ __launch_bounds__(TPB) void prep_kernel(
    const float* __restrict__ X, const float* __restrict__ S,
    const float* __restrict__ W1x, const float* __restrict__ W1s,
    ushortT* __restrict__ Ehl, ushortT* __restrict__ Ept) {
  __shared__ float wsh[256];
  __shared__ ushortT tl[16][272];
  const int tid = threadIdx.x;
  const int br = blockIdx.z;
  wsh[tid] = br ? W1s[tid] : W1x[tid];
  __syncthreads();
  const int n0 = blockIdx.x * 256;
  const int b = blockIdx.y;
  const int n = n0 + tid;
  const float SC = 1.2011224087f;  // sqrt(log2(e))
  const int wq = tid & 31;
  const int slot = (wq < 16) ? ((wq >> 2) * 8 + (wq & 3))
                             : (((wq - 16) >> 2) * 8 + 4 + (wq & 3));
  const int ptid = (tid & ~31) | slot;
  const float* In = br ? X : S;     // Xe uses S, Se uses X (cross-wired)

  float in[16];
#pragma unroll
  for (int l = 0; l < 16; ++l)
    in[l] = In[(size_t)(b * 16 + l) * NN + n];
  float e[16];
#pragma unroll
  for (int m = 0; m < 16; ++m) {
    float a0 = 0.f;
#pragma unroll
    for (int l = 0; l < 16; ++l) a0 = fmaf(in[l], wsh[l * 16 + m], a0);
    e[m] = a0;
  }
  const int bbr = br * 4 + b;
  unsigned int rw[16];
#pragma unroll
  for (int q = 0; q < 16; ++q) rw[q] = 0;
#pragma unroll
  for (int k = 0; k < 16; ++k) {
    const float vs = e[k] * SC;
    ushortT h = f2bf(vs);
    ushortT lo = f2bf(vs - bf2f(h));
    rw[k >> 1] |= ((unsigned int)h) << (16 * (k & 1));
    rw[8 + (k >> 1)] |= ((unsigned int)lo) << (16 * (k & 1));
    tl[k][ptid] = f2bf(e[k]);           // unscaled hi for PV operand
  }
  uint4* dst = (uint4*)(Ehl + ((size_t)bbr * NN + n) * 32);
  dst[0] = make_uint4(rw[0], rw[1], rw[2], rw[3]);
  dst[1] = make_uint4(rw[4], rw[5], rw[6], rw[7]);
  dst[2] = make_uint4(rw[8], rw[9], rw[10], rw[11]);
  dst[3] = make_uint4(rw[12], rw[13], rw[14], rw[15]);
  __syncthreads();
  {
    const int r = tid >> 4, c0 = (tid & 15) * 16;
    const uint4* src = (const uint4*)(&tl[r][c0]);
    uint4* d2 = (uint4*)(Ept + ((size_t)bbr * 16 + r) * NN + n0 + c0);
    d2[0] = src[0];
    d2[1] = src[1];
  }
}

// ---------------------------------------------------------------- pass A (32x32x16 MFMA)
// (R13-proven, verbatim.)
__global__ __launch_bounds__(TPB) void passA_kernel(
    const ushortT* __restrict__ Ehl, float* __restrict__ pmx,
    float* __restrict__ psm) {
  const int bid = blockIdx.x;
  const int bbr = bid & 7;
  const int ms = (bid >> 3) & 1;
  const int n0 = (bid >> 4) * 64;
  const int tid = threadIdx.x;
  const int w = tid >> 6, lane = tid & 63;
  const int lc = lane & 31;
  const int koff = (lane >> 5) * 8;      // k-slot offset for A/B frags
  const ushortT* Eb = Ehl + (size_t)bbr * NN * 32;

  short8v bh[2], bl[2];
#pragma unroll
  for (int s = 0; s < 2; ++s) {
    const ushortT* rp = Eb + (size_t)(n0 + s * 32 + lc) * 32;
    bh[s] = *(const short8v*)(rp + koff);
    bl[s] = *(const short8v*)(rp + 16 + koff);
  }
  float mx[2] = {-INFINITY, -INFINITY};
  float sm[2] = {0.f, 0.f};
  const f32x16 z16 = {0.f, 0.f, 0.f, 0.f, 0.f, 0.f, 0.f, 0.f,
                      0.f, 0.f, 0.f, 0.f, 0.f, 0.f, 0.f, 0.f};
  const ushortT* ap = Eb + (size_t)(ms * 2048 + w * 512 + lc) * 32;
  for (int ch = 0; ch < 16; ++ch) {
    short8v ah = *(const short8v*)(ap + koff);
    short8v al = *(const short8v*)(ap + 16 + koff);
    ap += 32 * 32;
#pragma unroll
    for (int s = 0; s < 2; ++s) {
      f32x16 c = __builtin_amdgcn_mfma_f32_32x32x16_bf16(ah, bh[s], z16, 0, 0, 0);
      c = __builtin_amdgcn_mfma_f32_32x32x16_bf16(al, bh[s], c, 0, 0, 0);
      c = __builtin_amdgcn_mfma_f32_32x32x16_bf16(ah, bl[s], c, 0, 0, 0);
      float t0 = fmaxf(fmaxf(c[0], c[1]), fmaxf(c[2], c[3]));
      float t1 = fmaxf(fmaxf(c[4], c[5]), fmaxf(c[6], c[7]));
      float t2 = fmaxf(fmaxf(c[8], c[9]), fmaxf(c[10], c[11]));
      float t3 = fmaxf(fmaxf(c[12], c[13]), fmaxf(c[14], c[15]));
      float tm = fmaxf(fmaxf(t0, t1), fmaxf(t2, t3));
      if (tm > mx[s] + 30.f) {            // deferred rescale (rare)
        sm[s] *= exp2a(mx[s] - tm);
        mx[s] = tm;
      }
      float e0 = exp2a(c[0] - mx[s]) + exp2a(c[1] - mx[s]);
      float e1 = exp2a(c[2] - mx[s]) + exp2a(c[3] - mx[s]);
      float e2 = exp2a(c[4] - mx[s]) + exp2a(c[5] - mx[s]);
      float e3 = exp2a(c[6] - mx[s]) + exp2a(c[7] - mx[s]);
      float e4 = exp2a(c[8] - mx[s]) + exp2a(c[9] - mx[s]);
      float e5 = exp2a(c[10] - mx[s]) + exp2a(c[11] - mx[s]);
      float e6 = exp2a(c[12] - mx[s]) + exp2a(c[13] - mx[s]);
      float e7 = exp2a(c[14] - mx[s]) + exp2a(c[15] - mx[s]);
      sm[s] += ((e0 + e1) + (e2 + e3)) + ((e4 + e5) + (e6 + e7));
    }
  }
#pragma unroll
  for (int s = 0; s < 2; ++s) {
    float omx = __shfl_xor(mx[s], 32);
    float osm = __shfl_xor(sm[s], 32);
    float nm = fmaxf(mx[s], omx);
    sm[s] = sm[s] * exp2a(mx[s] - nm) + osm * exp2a(omx - nm);
    mx[s] = nm;
  }
  __shared__ float smx[4][2][32], ssm[4][2][32];
  if (lane < 32) {
#pragma unroll
    for (int s = 0; s < 2; ++s) {
      smx[w][s][lc] = mx[s];
      ssm[w][s][lc] = sm[s];
    }
  }
  __syncthreads();
  if (tid < 64) {
    const int s = tid >> 5, col = tid & 31;
    float M = fmaxf(fmaxf(smx[0][s][col], smx[1][s][col]),
                    fmaxf(smx[2][s][col], smx[3][s][col]));
    float Ssum = ssm[0][s][col] * exp2a(smx[0][s][col] - M) +
                 ssm[1][s][col] * exp2a(smx[1][s][col] - M) +
                 ssm[2][s][col] * exp2a(smx[2][s][col] - M) +
                 ssm[3][s][col] * exp2a(smx[3][s][col] - M);
    const size_t o = (size_t)(ms * 8 + bbr) * NN + n0 + s * 32 + col;
    pmx[o] = M;
    psm[o] = Ssum;
  }
}

// ---------------------------------------------------------------- pass B
// (R12-proven, verbatim.) FUSED reduceA prologue; 64-m tile, 4 chains, SSA pk.
__global__ __launch_bounds__(TPB) void passB_kernel(
    const ushortT* __restrict__ Ehl, const ushortT* __restrict__ Ept,
    const float* __restrict__ pmx, const float* __restrict__ psm,
    float* __restrict__ pb) {
  const int bid = blockIdx.x;
  const int bbr = bid & 7;
  const int ns = (bid >> 3) & 1;
  const int m0 = (bid >> 4) * 64;
  const int tid = threadIdx.x;
  const int w = tid >> 6, lane = tid & 63;
  const int lr = lane & 15, g = lane >> 4;
  const ushortT* Eb = Ehl + (size_t)bbr * NN * 32;
  const ushortT* Tb = Ept + (size_t)bbr * 16 * NN;
  __shared__ float lsb[2048];
  __shared__ float red[4][4][16][17];
  for (int i = tid; i < 2048; i += TPB) {
    const size_t base = (size_t)bbr * NN + ns * 2048 + i;
    float m0v = pmx[base], m1v = pmx[32768 + base];
    float s0v = psm[base], s1v = psm[32768 + base];
    float M = fmaxf(m0v, m1v);
    float Ssum = s0v * exp2a(m0v - M) + s1v * exp2a(m1v - M);
    lsb[i] = -(M + log2f(fmaxf(Ssum, 1e-38f)));
  }
  __syncthreads();

  const short8v zero8 = {0, 0, 0, 0, 0, 0, 0, 0};
  short8v b1[4], b2[4];
#pragma unroll
  for (int s = 0; s < 4; ++s) {
    const ushortT* rp = Eb + (size_t)(m0 + s * 16 + lr) * 32;
    b1[s] = *(const short8v*)(rp + (g & 1) * 8);
    b2[s] = zero8;
    if (g < 2) b2[s] = *(const short8v*)(rp + 16 + g * 8);
  }
  f32x4 acc[4] = {{0.f, 0.f, 0.f, 0.f}, {0.f, 0.f, 0.f, 0.f},
                  {0.f, 0.f, 0.f, 0.f}, {0.f, 0.f, 0.f, 0.f}};
  const ushortT* ap = Eb + (size_t)(ns * 2048 + w * 512 + lr) * 32 + g * 8;
  const ushortT* vp = Tb + (size_t)lr * NN + ns * 2048 + w * 512 + g * 8;
  const float* lp = lsb + w * 512 + g * 4;
#pragma unroll 2
  for (int ch = 0; ch < 16; ++ch) {
    short8v a0 = *(const short8v*)ap;
    short8v a1 = *(const short8v*)(ap + 16 * 32);
    short8v ae = *(const short8v*)vp;
    f32x4 sd0 = *(const f32x4*)lp;          // -lse for rows nb+g*4..+3
    f32x4 sd1 = *(const f32x4*)(lp + 16);   // -lse for rows nb+16+g*4..+3
    ap += 32 * 32; vp += 32; lp += 32;
#pragma unroll
    for (int s = 0; s < 4; ++s) {
      f32x4 c0 = __builtin_amdgcn_mfma_f32_16x16x32_bf16(a0, b1[s], sd0, 0, 0, 0);
      c0 = __builtin_amdgcn_mfma_f32_16x16x32_bf16(a0, b2[s], c0, 0, 0, 0);
      f32x4 c1 = __builtin_amdgcn_mfma_f32_16x16x32_bf16(a1, b1[s], sd1, 0, 0, 0);
      c1 = __builtin_amdgcn_mfma_f32_16x16x32_bf16(a1, b2[s], c1, 0, 0, 0);
      float p0 = exp2a(c0[0]), p1 = exp2a(c0[1]);
      float p2 = exp2a(c0[2]), p3 = exp2a(c0[3]);
      float q0 = exp2a(c1[0]), q1 = exp2a(c1[1]);
      float q2 = exp2a(c1[2]), q3 = exp2a(c1[3]);
      unsigned int u0, u1, u2, u3;
      asm("v_cvt_pk_bf16_f32 %0, %1, %2" : "=v"(u0) : "v"(p0), "v"(p1));
      asm("v_cvt_pk_bf16_f32 %0, %1, %2" : "=v"(u1) : "v"(p2), "v"(p3));
      asm("v_cvt_pk_bf16_f32 %0, %1, %2" : "=v"(u2) : "v"(q0), "v"(q1));
      asm("v_cvt_pk_bf16_f32 %0, %1, %2" : "=v"(u3) : "v"(q2), "v"(q3));
      const uint4 uv = make_uint4(u0, u1, u2, u3);
      const short8v pf = __builtin_bit_cast(short8v, uv);
      acc[s] = __builtin_amdgcn_mfma_f32_16x16x32_bf16(ae, pf, acc[s], 0, 0, 0);
    }
  }
#pragma unroll
  for (int s = 0; s < 4; ++s)
#pragma unroll
    for (int r = 0; r < 4; ++r) red[w][s][g * 4 + r][lr] = acc[s][r];
  __syncthreads();
  for (int o = tid; o < 1024; o += TPB) {
    const int s = o >> 8, l = (o >> 4) & 15, mm = o & 15;
    float v = red[0][s][l][mm] + red[1][s][l][mm] +
              red[2][s][l][mm] + red[3][s][l][mm];
    pb[((size_t)(ns * 8 + bbr) * 16 + l) * NN + m0 + s * 16 + mm] = v;
  }
}

// ---------------------------------------------------------------- reduce B
__global__ __launch_bounds__(TPB) void reduceB_kernel(
    const float* __restrict__ pb, ushortT* __restrict__ EaT) {
  const int gidx = blockIdx.x * TPB + threadIdx.x;   // 0..131071
  const int r = gidx >> 10;                          // bbr*16 + l
  const int j4 = gidx & 1023;
  const float4 p0 = *(const float4*)(pb + (size_t)r * NN + j4 * 4);
  const float4 p1 = *(const float4*)(pb + (size_t)(128 + r) * NN + j4 * 4);
  const float v0 = p0.x + p1.x, v1 = p0.y + p1.y;
  const float v2 = p0.z + p1.z, v3 = p0.w + p1.w;
  const int bbr = r >> 4, l = r & 15;
  unsigned int ue, uo;
  asm("v_cvt_pk_bf16_f32 %0, %1, %2" : "=v"(ue) : "v"(v0), "v"(v2));
  asm("v_cvt_pk_bf16_f32 %0, %1, %2" : "=v"(uo) : "v"(v1), "v"(v3));
  *(unsigned int*)(EaT + ((size_t)(bbr * 2 + 0) * 16 + l) * KK + j4 * 2) = ue;
  *(unsigned int*)(EaT + ((size_t)(bbr * 2 + 1) * 16 + l) * KK + j4 * 2) = uo;
}

// ---------------------------------------------------------------- M-mix (MFMA), k-split x4 -> f32 partials
// DEEP PREFETCH: all 8 chunks' W2 loads issued at block start (32 regs,
// static indices); per chunk: cvt -> LDS -> sync -> MFMA (1 sync, 2 buffers).
__global__ __launch_bounds__(TPB) void mmix_kernel(
    const ushortT* __restrict__ EaT,
    const float* __restrict__ W2x, const float* __restrict__ W2s,
    float* __restrict__ pmm) {
  const int jt = blockIdx.x;   // 0..127
  const int br = blockIdx.y;   // 0..1
  const int ks = blockIdx.z;   // 0..3 (512-row K slice)
  const float* W2 = br ? W2s : W2x;
  const int j0 = jt * 16;
  const int kb = ks * 512;
  const int tid = threadIdx.x;
  const int w = tid >> 6, lane = tid & 63;
  const int b = w;
  const int lj = tid & 15, kp0 = tid >> 4;
  const int fl = lane & 15, g = lane >> 4;
  __shared__ ushortT bpan[2][16][72];

  const size_t rb0 = ((size_t)(br * 4 + b) * 2 + 0) * 16;
  const size_t rb1 = ((size_t)(br * 4 + b) * 2 + 1) * 16;

  f32x4 acc0 = {0.f, 0.f, 0.f, 0.f};
  f32x4 acc1 = {0.f, 0.f, 0.f, 0.f};

  // issue ALL W2 loads up front (one HBM round-trip for the whole block)
  float w2r[8][4];
#pragma unroll
  for (int c = 0; c < 8; ++c) {
    const int kc = kb + c * 64;
    w2r[c][0] = W2[(size_t)(kc + 2 * kp0)      * KK + j0 + lj];
    w2r[c][1] = W2[(size_t)(kc + 2 * kp0 + 1)  * KK + j0 + lj];
    w2r[c][2] = W2[(size_t)(kc + 2 * kp0 + 32) * KK + j0 + lj];
    w2r[c][3] = W2[(size_t)(kc + 2 * kp0 + 33) * KK + j0 + lj];
  }

#pragma unroll
  for (int c = 0; c < 8; ++c) {
    const int cur = c & 1;
    unsigned int u0, u1;
    asm("v_cvt_pk_bf16_f32 %0, %1, %2" : "=v"(u0) : "v"(w2r[c][0]), "v"(w2r[c][1]));
    asm("v_cvt_pk_bf16_f32 %0, %1, %2" : "=v"(u1) : "v"(w2r[c][2]), "v"(w2r[c][3]));
    *(unsigned int*)(&bpan[cur][lj][kp0 * 2]) = u0;
    *(unsigned int*)(&bpan[cur][lj][(kp0 + 16) * 2]) = u1;
    __syncthreads();
#pragma unroll
    for (int s = 0; s < 2; ++s) {
      const int k = kb + c * 64 + s * 32 + g * 8;
      short8v bf = *(const short8v*)(&bpan[cur][fl][s * 32 + g * 8]);
      short8v a0 = *(const short8v*)(EaT + (rb0 + fl) * (size_t)KK + k);
      short8v a1 = *(const short8v*)(EaT + (rb1 + fl) * (size_t)KK + k);
      acc0 = __builtin_amdgcn_mfma_f32_16x16x32_bf16(a0, bf, acc0, 0, 0, 0);
      acc1 = __builtin_amdgcn_mfma_f32_16x16x32_bf16(a1, bf, acc1, 0, 0, 0);
    }
  }

  const int j = j0 + fl;
#pragma unroll
  for (int r = 0; r < 4; ++r) {
    const int l = g * 4 + r;
    const size_t base = ((size_t)(ks * 2 + br) * 4 + b) * 2;
    pmm[((base + 0) * 16 + l) * (size_t)KK + j] = acc0[r];
    pmm[((base + 1) * 16 + l) * (size_t)KK + j] = acc1[r];
  }
}

// ---------------------------------------------------------------- 3x3 SAME conv, H=2048 W=2
// COUT-SPLIT x2: blockIdx.z = br*2 + cout-half; wts LDS 18 KB; grid 1024.
__global__ __launch_bounds__(TPB) void conv_kernel(
    const float* __restrict__ pmm,
    const float* __restrict__ X, const float* __restrict__ S,
    const float* __restrict__ Wx, const float* __restrict__ Bx,
    const float* __restrict__ Ws, const float* __restrict__ Bs,
    float* __restrict__ out) {
  const int kt = blockIdx.x;   // 0..63
  const int b = blockIdx.y;
  const int z = blockIdx.z;    // 0..3
  const int br = z >> 1, ch = z & 1;
  const float* Wt = br ? Ws : Wx;
  const float* Bi = br ? Bs : Bx;
  const float* Inp = br ? S : X;
  __shared__ float inT[32 * 34 * 2];     // [cin][34][2] halo rows
  __shared__ float wts[16 * 289];
  const int tid = threadIdx.x;
  const int k0 = kt * 32;

  for (int f = tid; f < 16 * 288; f += TPB) {
    const int c = f / 288, rem = f % 288;
    wts[c * 289 + rem] = Wt[(ch * 16 + c) * 288 + rem];
  }
  for (int f = tid; f < 32 * 34 * 2; f += TPB) {
    const int cin = f / 68, rem = f % 68;
    const int kk = rem >> 1, t = rem & 1;
    const int j = k0 - 1 + kk;
    float v = 0.f;
    if (j >= 0 && j < KK) {
      const int l = cin & 15;
      const float inv = Inp[(size_t)(b * 16 + l) * NN + 2 * j + t];
      if (cin < 16) {
        float sum = 0.f;
#pragma unroll
        for (int ks = 0; ks < 4; ++ks)
          sum += pmm[((((size_t)(ks * 2 + br) * 4 + b) * 2 + t) * 16 + l) *
                         (size_t)KK + j];
        if (br == 0) {
          v = sum * inv;
        } else {
          const float pe = t ? cosf((float)j) : sinf((float)j);
          v = fmaf(sum, inv, pe);
        }
      } else {
        if (br == 0) {
          v = inv;
        } else {
          const float pe = t ? cosf((float)j) : sinf((float)j);
          v = inv + pe;
        }
      }
    }
    inT[f] = v;
  }
  __syncthreads();

  const int c = tid >> 4, sub = tid & 15;
  const float bias = Bi[ch * 16 + c];
  float acc0[2], acc1[2];
#pragma unroll
  for (int i = 0; i < 2; ++i) { acc0[i] = bias; acc1[i] = bias; }

  for (int cin = 0; cin < 32; ++cin) {
    const float* wp = wts + c * 289 + cin * 9;
    const float w00 = wp[0], w01 = wp[1], w02 = wp[2];
    const float w10 = wp[3], w11 = wp[4], w12 = wp[5];
    const float w20 = wp[6], w21 = wp[7], w22 = wp[8];
    const float* ip = inT + cin * 68;
#pragma unroll
    for (int i = 0; i < 2; ++i) {
      const int kl = sub + 16 * i;
      const float* q = ip + kl * 2;
      const float i00 = q[0], i01 = q[1];
      const float i10 = q[2], i11 = q[3];
      const float i20 = q[4], i21 = q[5];
      acc0[i] = fmaf(i00, w01, acc0[i]); acc0[i] = fmaf(i01, w02, acc0[i]);
      acc0[i] = fmaf(i10, w11, acc0[i]); acc0[i] = fmaf(i11, w12, acc0[i]);
      acc0[i] = fmaf(i20, w21, acc0[i]); acc0[i] = fmaf(i21, w22, acc0[i]);
      acc1[i] = fmaf(i00, w00, acc1[i]); acc1[i] = fmaf(i01, w01, acc1[i]);
      acc1[i] = fmaf(i10, w10, acc1[i]); acc1[i] = fmaf(i11, w11, acc1[i]);
      acc1[i] = fmaf(i20, w20, acc1[i]); acc1[i] = fmaf(i21, w21, acc1[i]);
    }
  }
#pragma unroll
  for (int i = 0; i < 2; ++i) {
    const int k = k0 + sub + 16 * i;
    const size_t o = ((size_t)(b * 64 + br * 32 + ch * 16 + c) * KK + k) * 2;
    out[o] = acc0[i];
    out[o + 1] = acc1[i];
  }
}

// ---------------------------------------------------------------- launch
extern "C" void kernel_launch(void* const* d_in, const int* in_sizes, int n_in,
                              void* d_out, int out_size, void* d_ws, size_t ws_size,
                              hipStream_t stream) {
  (void)in_sizes; (void)n_in; (void)out_size; (void)ws_size;
  const float* X   = (const float*)d_in[0];
  const float* S   = (const float*)d_in[1];
  const float* W1x = (const float*)d_in[2];
  const float* W1s = (const float*)d_in[3];
  const float* W2x = (const float*)d_in[4];
  const float* W2s = (const float*)d_in[5];
  const float* Cwx = (const float*)d_in[6];
  const float* Cbx = (const float*)d_in[7];
  const float* Cws = (const float*)d_in[8];
  const float* Cbs = (const float*)d_in[9];
  float* out = (float*)d_out;
  float* ws = (float*)d_ws;

  ushortT* Ehl = (ushortT*)(ws + OFF_EHL);
  ushortT* Ept = (ushortT*)(ws + OFF_ET);
  ushortT* EaT = (ushortT*)(ws + OFF_EAT);
  float*   pb  = ws + OFF_PB;
  float*   pmx = ws + OFF_PMX;
  float*   psm = ws + OFF_PSM;
  float*   pmm = ws + OFF_PMM;

  hipLaunchKernelGGL(prep_kernel, dim3(16, NBATCH, 2), dim3(TPB), 0, stream,
                     X, S, W1x, W1s, Ehl, Ept);
  hipLaunchKernelGGL(passA_kernel, dim3(1024), dim3(TPB), 0, stream,
                     Ehl, pmx, psm);
  hipLaunchKernelGGL(passB_kernel, dim3(1024), dim3(TPB), 0, stream,
                     Ehl, Ept, pmx, psm, pb);
  hipLaunchKernelGGL(reduceB_kernel, dim3(512), dim3(TPB), 0, stream,
                     pb, EaT);
  hipLaunchKernelGGL(mmix_kernel, dim3(128, 2, 4), dim3(TPB), 0, stream,
                     EaT, W2x, W2s, pmm);
  hipLaunchKernelGGL(conv_kernel, dim3(64, NBATCH, 4), dim3(TPB), 0, stream,
                     pmm, X, S, Cwx, Cbx, Cws, Cbs, out);
}

// Round 15
// 111.879 us; speedup vs baseline: 1.0071x; 1.0071x over previous
//
#include <hip/hip_runtime.h>
#include <math.h>

#define TPB 256

static constexpr int LL = 16;
static constexpr int KK = 2048;
static constexpr int NBATCH = 4;
static constexpr int NN = 4096;        // K*B
static constexpr int BBR = 8;          // (branch, batch) combos

// workspace layout in float slots (ws is ~268MB)
static constexpr size_t OFF_EHL = 0;          // 8*4096*32 bf16 = 524288 f
static constexpr size_t OFF_ET  = 524288;     // 8*16*4096 bf16 = 262144 f (n-permuted)
static constexpr size_t OFF_EAT = 819200;     // 8*2*16*2048 bf16 = 262144 f
static constexpr size_t OFF_PB  = 2129920;    // 2*8*16*4096 f32 = 1048576 f
static constexpr size_t OFF_PMX = 3178496;    // 2*8*4096 f32 = 65536 f
static constexpr size_t OFF_PSM = 3244032;    // 65536 f
static constexpr size_t OFF_PMM = 3309568;    // 4ks*2br*4b*2t*16l*2048j f32 = 2097152 f

typedef unsigned short ushortT;
typedef __attribute__((ext_vector_type(8))) short short8v;
typedef __attribute__((ext_vector_type(4))) float f32x4;
typedef __attribute__((ext_vector_type(16))) float f32x16;

__device__ __forceinline__ ushortT f2bf(float x) {
  union { float f; unsigned int u; } c; c.f = x;
  unsigned int u = c.u;
  return (ushortT)((u + 0x7FFFu + ((u >> 16) & 1u)) >> 16);
}
__device__ __forceinline__ float bf2f(ushortT h) {
  union { unsigned int u; float f; } c; c.u = ((unsigned int)h) << 16;
  return c.f;
}
__device__ __forceinline__ float exp2a(float x) {
  float r; asm("v_exp_f32 %0, %1" : "=v"(r) : "v"(x)); return r;
}

// ---------------------------------------------------------------- prep
// (R8-proven, verbatim.) One branch per blockIdx.z.
__global__ __launch_bounds__(TPB) void prep_kernel(
    const float* __restrict__ X, const float* __restrict__ S,
    const float* __restrict__ W1x, const float* __restrict__ W1s,
    ushortT* __restrict__ Ehl, ushortT* __restrict__ Ept) {
  __shared__ float wsh[256];
  __shared__ ushortT tl[16][272];
  const int tid = threadIdx.x;
  const int br = blockIdx.z;
  wsh[tid] = br ? W1s[tid] : W1x[tid];
  __syncthreads();
  const int n0 = blockIdx.x * 256;
  const int b = blockIdx.y;
  const int n = n0 + tid;
  const float SC = 1.2011224087f;  // sqrt(log2(e))
  const int wq = tid & 31;
  const int slot = (wq < 16) ? ((wq >> 2) * 8 + (wq & 3))
                             : (((wq - 16) >> 2) * 8 + 4 + (wq & 3));
  const int ptid = (tid & ~31) | slot;
  const float* In = br ? X : S;     // Xe uses S, Se uses X (cross-wired)

  float in[16];
#pragma unroll
  for (int l = 0; l < 16; ++l)
    in[l] = In[(size_t)(b * 16 + l) * NN + n];
  float e[16];
#pragma unroll
  for (int m = 0; m < 16; ++m) {
    float a0 = 0.f;
#pragma unroll
    for (int l = 0; l < 16; ++l) a0 = fmaf(in[l], wsh[l * 16 + m], a0);
    e[m] = a0;
  }
  const int bbr = br * 4 + b;
  unsigned int rw[16];
#pragma unroll
  for (int q = 0; q < 16; ++q) rw[q] = 0;
#pragma unroll
  for (int k = 0; k < 16; ++k) {
    const float vs = e[k] * SC;
    ushortT h = f2bf(vs);
    ushortT lo = f2bf(vs - bf2f(h));
    rw[k >> 1] |= ((unsigned int)h) << (16 * (k & 1));
    rw[8 + (k >> 1)] |= ((unsigned int)lo) << (16 * (k & 1));
    tl[k][ptid] = f2bf(e[k]);           // unscaled hi for PV operand
  }
  uint4* dst = (uint4*)(Ehl + ((size_t)bbr * NN + n) * 32);
  dst[0] = make_uint4(rw[0], rw[1], rw[2], rw[3]);
  dst[1] = make_uint4(rw[4], rw[5], rw[6], rw[7]);
  dst[2] = make_uint4(rw[8], rw[9], rw[10], rw[11]);
  dst[3] = make_uint4(rw[12], rw[13], rw[14], rw[15]);
  __syncthreads();
  {
    const int r = tid >> 4, c0 = (tid & 15) * 16;
    const uint4* src = (const uint4*)(&tl[r][c0]);
    uint4* d2 = (uint4*)(Ept + ((size_t)bbr * 16 + r) * NN + n0 + c0);
    d2[0] = src[0];
    d2[1] = src[1];
  }
}

// ---------------------------------------------------------------- pass A (32x32x16 MFMA)
// (R13-proven, verbatim.)
__global__ __launch_bounds__(TPB) void passA_kernel(
    const ushortT* __restrict__ Ehl, float* __restrict__ pmx,
    float* __restrict__ psm) {
  const int bid = blockIdx.x;
  const int bbr = bid & 7;
  const int ms = (bid >> 3) & 1;
  const int n0 = (bid >> 4) * 64;
  const int tid = threadIdx.x;
  const int w = tid >> 6, lane = tid & 63;
  const int lc = lane & 31;
  const int koff = (lane >> 5) * 8;      // k-slot offset for A/B frags
  const ushortT* Eb = Ehl + (size_t)bbr * NN * 32;

  short8v bh[2], bl[2];
#pragma unroll
  for (int s = 0; s < 2; ++s) {
    const ushortT* rp = Eb + (size_t)(n0 + s * 32 + lc) * 32;
    bh[s] = *(const short8v*)(rp + koff);
    bl[s] = *(const short8v*)(rp + 16 + koff);
  }
  float mx[2] = {-INFINITY, -INFINITY};
  float sm[2] = {0.f, 0.f};
  const f32x16 z16 = {0.f, 0.f, 0.f, 0.f, 0.f, 0.f, 0.f, 0.f,
                      0.f, 0.f, 0.f, 0.f, 0.f, 0.f, 0.f, 0.f};
  const ushortT* ap = Eb + (size_t)(ms * 2048 + w * 512 + lc) * 32;
  for (int ch = 0; ch < 16; ++ch) {
    short8v ah = *(const short8v*)(ap + koff);
    short8v al = *(const short8v*)(ap + 16 + koff);
    ap += 32 * 32;
#pragma unroll
    for (int s = 0; s < 2; ++s) {
      f32x16 c = __builtin_amdgcn_mfma_f32_32x32x16_bf16(ah, bh[s], z16, 0, 0, 0);
      c = __builtin_amdgcn_mfma_f32_32x32x16_bf16(al, bh[s], c, 0, 0, 0);
      c = __builtin_amdgcn_mfma_f32_32x32x16_bf16(ah, bl[s], c, 0, 0, 0);
      float t0 = fmaxf(fmaxf(c[0], c[1]), fmaxf(c[2], c[3]));
      float t1 = fmaxf(fmaxf(c[4], c[5]), fmaxf(c[6], c[7]));
      float t2 = fmaxf(fmaxf(c[8], c[9]), fmaxf(c[10], c[11]));
      float t3 = fmaxf(fmaxf(c[12], c[13]), fmaxf(c[14], c[15]));
      float tm = fmaxf(fmaxf(t0, t1), fmaxf(t2, t3));
      if (tm > mx[s] + 30.f) {            // deferred rescale (rare)
        sm[s] *= exp2a(mx[s] - tm);
        mx[s] = tm;
      }
      float e0 = exp2a(c[0] - mx[s]) + exp2a(c[1] - mx[s]);
      float e1 = exp2a(c[2] - mx[s]) + exp2a(c[3] - mx[s]);
      float e2 = exp2a(c[4] - mx[s]) + exp2a(c[5] - mx[s]);
      float e3 = exp2a(c[6] - mx[s]) + exp2a(c[7] - mx[s]);
      float e4 = exp2a(c[8] - mx[s]) + exp2a(c[9] - mx[s]);
      float e5 = exp2a(c[10] - mx[s]) + exp2a(c[11] - mx[s]);
      float e6 = exp2a(c[12] - mx[s]) + exp2a(c[13] - mx[s]);
      float e7 = exp2a(c[14] - mx[s]) + exp2a(c[15] - mx[s]);
      sm[s] += ((e0 + e1) + (e2 + e3)) + ((e4 + e5) + (e6 + e7));
    }
  }
#pragma unroll
  for (int s = 0; s < 2; ++s) {
    float omx = __shfl_xor(mx[s], 32);
    float osm = __shfl_xor(sm[s], 32);
    float nm = fmaxf(mx[s], omx);
    sm[s] = sm[s] * exp2a(mx[s] - nm) + osm * exp2a(omx - nm);
    mx[s] = nm;
  }
  __shared__ float smx[4][2][32], ssm[4][2][32];
  if (lane < 32) {
#pragma unroll
    for (int s = 0; s < 2; ++s) {
      smx[w][s][lc] = mx[s];
      ssm[w][s][lc] = sm[s];
    }
  }
  __syncthreads();
  if (tid < 64) {
    const int s = tid >> 5, col = tid & 31;
    float M = fmaxf(fmaxf(smx[0][s][col], smx[1][s][col]),
                    fmaxf(smx[2][s][col], smx[3][s][col]));
    float Ssum = ssm[0][s][col] * exp2a(smx[0][s][col] - M) +
                 ssm[1][s][col] * exp2a(smx[1][s][col] - M) +
                 ssm[2][s][col] * exp2a(smx[2][s][col] - M) +
                 ssm[3][s][col] * exp2a(smx[3][s][col] - M);
    const size_t o = (size_t)(ms * 8 + bbr) * NN + n0 + s * 32 + col;
    pmx[o] = M;
    psm[o] = Ssum;
  }
}

// ---------------------------------------------------------------- pass B
// (R12-proven, verbatim.) FUSED reduceA prologue; 64-m tile, 4 chains, SSA pk.
__global__ __launch_bounds__(TPB) void passB_kernel(
    const ushortT* __restrict__ Ehl, const ushortT* __restrict__ Ept,
    const float* __restrict__ pmx, const float* __restrict__ psm,
    float* __restrict__ pb) {
  const int bid = blockIdx.x;
  const int bbr = bid & 7;
  const int ns = (bid >> 3) & 1;
  const int m0 = (bid >> 4) * 64;
  const int tid = threadIdx.x;
  const int w = tid >> 6, lane = tid & 63;
  const int lr = lane & 15, g = lane >> 4;
  const ushortT* Eb = Ehl + (size_t)bbr * NN * 32;
  const ushortT* Tb = Ept + (size_t)bbr * 16 * NN;
  __shared__ float lsb[2048];
  __shared__ float red[4][4][16][17];
  for (int i = tid; i < 2048; i += TPB) {
    const size_t base = (size_t)bbr * NN + ns * 2048 + i;
    float m0v = pmx[base], m1v = pmx[32768 + base];
    float s0v = psm[base], s1v = psm[32768 + base];
    float M = fmaxf(m0v, m1v);
    float Ssum = s0v * exp2a(m0v - M) + s1v * exp2a(m1v - M);
    lsb[i] = -(M + log2f(fmaxf(Ssum, 1e-38f)));
  }
  __syncthreads();

  const short8v zero8 = {0, 0, 0, 0, 0, 0, 0, 0};
  short8v b1[4], b2[4];
#pragma unroll
  for (int s = 0; s < 4; ++s) {
    const ushortT* rp = Eb + (size_t)(m0 + s * 16 + lr) * 32;
    b1[s] = *(const short8v*)(rp + (g & 1) * 8);
    b2[s] = zero8;
    if (g < 2) b2[s] = *(const short8v*)(rp + 16 + g * 8);
  }
  f32x4 acc[4] = {{0.f, 0.f, 0.f, 0.f}, {0.f, 0.f, 0.f, 0.f},
                  {0.f, 0.f, 0.f, 0.f}, {0.f, 0.f, 0.f, 0.f}};
  const ushortT* ap = Eb + (size_t)(ns * 2048 + w * 512 + lr) * 32 + g * 8;
  const ushortT* vp = Tb + (size_t)lr * NN + ns * 2048 + w * 512 + g * 8;
  const float* lp = lsb + w * 512 + g * 4;
#pragma unroll 2
  for (int ch = 0; ch < 16; ++ch) {
    short8v a0 = *(const short8v*)ap;
    short8v a1 = *(const short8v*)(ap + 16 * 32);
    short8v ae = *(const short8v*)vp;
    f32x4 sd0 = *(const f32x4*)lp;          // -lse for rows nb+g*4..+3
    f32x4 sd1 = *(const f32x4*)(lp + 16);   // -lse for rows nb+16+g*4..+3
    ap += 32 * 32; vp += 32; lp += 32;
#pragma unroll
    for (int s = 0; s < 4; ++s) {
      f32x4 c0 = __builtin_amdgcn_mfma_f32_16x16x32_bf16(a0, b1[s], sd0, 0, 0, 0);
      c0 = __builtin_amdgcn_mfma_f32_16x16x32_bf16(a0, b2[s], c0, 0, 0, 0);
      f32x4 c1 = __builtin_amdgcn_mfma_f32_16x16x32_bf16(a1, b1[s], sd1, 0, 0, 0);
      c1 = __builtin_amdgcn_mfma_f32_16x16x32_bf16(a1, b2[s], c1, 0, 0, 0);
      float p0 = exp2a(c0[0]), p1 = exp2a(c0[1]);
      float p2 = exp2a(c0[2]), p3 = exp2a(c0[3]);
      float q0 = exp2a(c1[0]), q1 = exp2a(c1[1]);
      float q2 = exp2a(c1[2]), q3 = exp2a(c1[3]);
      unsigned int u0, u1, u2, u3;
      asm("v_cvt_pk_bf16_f32 %0, %1, %2" : "=v"(u0) : "v"(p0), "v"(p1));
      asm("v_cvt_pk_bf16_f32 %0, %1, %2" : "=v"(u1) : "v"(p2), "v"(p3));
      asm("v_cvt_pk_bf16_f32 %0, %1, %2" : "=v"(u2) : "v"(q0), "v"(q1));
      asm("v_cvt_pk_bf16_f32 %0, %1, %2" : "=v"(u3) : "v"(q2), "v"(q3));
      const uint4 uv = make_uint4(u0, u1, u2, u3);
      const short8v pf = __builtin_bit_cast(short8v, uv);
      acc[s] = __builtin_amdgcn_mfma_f32_16x16x32_bf16(ae, pf, acc[s], 0, 0, 0);
    }
  }
#pragma unroll
  for (int s = 0; s < 4; ++s)
#pragma unroll
    for (int r = 0; r < 4; ++r) red[w][s][g * 4 + r][lr] = acc[s][r];
  __syncthreads();
  for (int o = tid; o < 1024; o += TPB) {
    const int s = o >> 8, l = (o >> 4) & 15, mm = o & 15;
    float v = red[0][s][l][mm] + red[1][s][l][mm] +
              red[2][s][l][mm] + red[3][s][l][mm];
    pb[((size_t)(ns * 8 + bbr) * 16 + l) * NN + m0 + s * 16 + mm] = v;
  }
}

// ---------------------------------------------------------------- reduce B
__global__ __launch_bounds__(TPB) void reduceB_kernel(
    const float* __restrict__ pb, ushortT* __restrict__ EaT) {
  const int gidx = blockIdx.x * TPB + threadIdx.x;   // 0..131071
  const int r = gidx >> 10;                          // bbr*16 + l
  const int j4 = gidx & 1023;
  const float4 p0 = *(const float4*)(pb + (size_t)r * NN + j4 * 4);
  const float4 p1 = *(const float4*)(pb + (size_t)(128 + r) * NN + j4 * 4);
  const float v0 = p0.x + p1.x, v1 = p0.y + p1.y;
  const float v2 = p0.z + p1.z, v3 = p0.w + p1.w;
  const int bbr = r >> 4, l = r & 15;
  unsigned int ue, uo;
  asm("v_cvt_pk_bf16_f32 %0, %1, %2" : "=v"(ue) : "v"(v0), "v"(v2));
  asm("v_cvt_pk_bf16_f32 %0, %1, %2" : "=v"(uo) : "v"(v1), "v"(v3));
  *(unsigned int*)(EaT + ((size_t)(bbr * 2 + 0) * 16 + l) * KK + j4 * 2) = ue;
  *(unsigned int*)(EaT + ((size_t)(bbr * 2 + 1) * 16 + l) * KK + j4 * 2) = uo;
}

// ---------------------------------------------------------------- M-mix (MFMA), k-split x4 -> f32 partials
// DEEP PREFETCH (kept from R14): all 8 chunks' W2 loads issued at block start.
__global__ __launch_bounds__(TPB) void mmix_kernel(
    const ushortT* __restrict__ EaT,
    const float* __restrict__ W2x, const float* __restrict__ W2s,
    float* __restrict__ pmm) {
  const int jt = blockIdx.x;   // 0..127
  const int br = blockIdx.y;   // 0..1
  const int ks = blockIdx.z;   // 0..3 (512-row K slice)
  const float* W2 = br ? W2s : W2x;
  const int j0 = jt * 16;
  const int kb = ks * 512;
  const int tid = threadIdx.x;
  const int w = tid >> 6, lane = tid & 63;
  const int b = w;
  const int lj = tid & 15, kp0 = tid >> 4;
  const int fl = lane & 15, g = lane >> 4;
  __shared__ ushortT bpan[2][16][72];

  const size_t rb0 = ((size_t)(br * 4 + b) * 2 + 0) * 16;
  const size_t rb1 = ((size_t)(br * 4 + b) * 2 + 1) * 16;

  f32x4 acc0 = {0.f, 0.f, 0.f, 0.f};
  f32x4 acc1 = {0.f, 0.f, 0.f, 0.f};

  // issue ALL W2 loads up front (one HBM round-trip for the whole block)
  float w2r[8][4];
#pragma unroll
  for (int c = 0; c < 8; ++c) {
    const int kc = kb + c * 64;
    w2r[c][0] = W2[(size_t)(kc + 2 * kp0)      * KK + j0 + lj];
    w2r[c][1] = W2[(size_t)(kc + 2 * kp0 + 1)  * KK + j0 + lj];
    w2r[c][2] = W2[(size_t)(kc + 2 * kp0 + 32) * KK + j0 + lj];
    w2r[c][3] = W2[(size_t)(kc + 2 * kp0 + 33) * KK + j0 + lj];
  }

#pragma unroll
  for (int c = 0; c < 8; ++c) {
    const int cur = c & 1;
    unsigned int u0, u1;
    asm("v_cvt_pk_bf16_f32 %0, %1, %2" : "=v"(u0) : "v"(w2r[c][0]), "v"(w2r[c][1]));
    asm("v_cvt_pk_bf16_f32 %0, %1, %2" : "=v"(u1) : "v"(w2r[c][2]), "v"(w2r[c][3]));
    *(unsigned int*)(&bpan[cur][lj][kp0 * 2]) = u0;
    *(unsigned int*)(&bpan[cur][lj][(kp0 + 16) * 2]) = u1;
    __syncthreads();
#pragma unroll
    for (int s = 0; s < 2; ++s) {
      const int k = kb + c * 64 + s * 32 + g * 8;
      short8v bf = *(const short8v*)(&bpan[cur][fl][s * 32 + g * 8]);
      short8v a0 = *(const short8v*)(EaT + (rb0 + fl) * (size_t)KK + k);
      short8v a1 = *(const short8v*)(EaT + (rb1 + fl) * (size_t)KK + k);
      acc0 = __builtin_amdgcn_mfma_f32_16x16x32_bf16(a0, bf, acc0, 0, 0, 0);
      acc1 = __builtin_amdgcn_mfma_f32_16x16x32_bf16(a1, bf, acc1, 0, 0, 0);
    }
  }

  const int j = j0 + fl;
#pragma unroll
  for (int r = 0; r < 4; ++r) {
    const int l = g * 4 + r;
    const size_t base = ((size_t)(ks * 2 + br) * 4 + b) * 2;
    pmm[((base + 0) * 16 + l) * (size_t)KK + j] = acc0[r];
    pmm[((base + 1) * 16 + l) * (size_t)KK + j] = acc1[r];
  }
}

// ---------------------------------------------------------------- 3x3 SAME conv, H=2048 W=2
// (R13-proven, verbatim — cout-split REVERTED.) FUSED mergeM.
__global__ __launch_bounds__(TPB) void conv_kernel(
    const float* __restrict__ pmm,
    const float* __restrict__ X, const float* __restrict__ S,
    const float* __restrict__ Wx, const float* __restrict__ Bx,
    const float* __restrict__ Ws, const float* __restrict__ Bs,
    float* __restrict__ out) {
  const int kt = blockIdx.x;   // 0..63
  const int b = blockIdx.y;
  const int br = blockIdx.z;
  const float* Wt = br ? Ws : Wx;
  const float* Bi = br ? Bs : Bx;
  const float* Inp = br ? S : X;
  __shared__ float inT[32 * 34 * 2];     // [cin][34][2] halo rows
  __shared__ float wts[32 * 289];
  const int tid = threadIdx.x;
  const int k0 = kt * 32;

  for (int f = tid; f < 32 * 288; f += TPB) {
    const int c = f / 288, rem = f % 288;
    wts[c * 289 + rem] = Wt[f];
  }
  for (int f = tid; f < 32 * 34 * 2; f += TPB) {
    const int cin = f / 68, rem = f % 68;
    const int kk = rem >> 1, t = rem & 1;
    const int j = k0 - 1 + kk;
    float v = 0.f;
    if (j >= 0 && j < KK) {
      const int l = cin & 15;
      const float inv = Inp[(size_t)(b * 16 + l) * NN + 2 * j + t];
      if (cin < 16) {
        float sum = 0.f;
#pragma unroll
        for (int ks = 0; ks < 4; ++ks)
          sum += pmm[((((size_t)(ks * 2 + br) * 4 + b) * 2 + t) * 16 + l) *
                         (size_t)KK + j];
        if (br == 0) {
          v = sum * inv;
        } else {
          const float pe = t ? cosf((float)j) : sinf((float)j);
          v = fmaf(sum, inv, pe);
        }
      } else {
        if (br == 0) {
          v = inv;
        } else {
          const float pe = t ? cosf((float)j) : sinf((float)j);
          v = inv + pe;
        }
      }
    }
    inT[f] = v;
  }
  __syncthreads();

  const int c = tid >> 3, sub = tid & 7;
  const float bias = Bi[c];
  float acc0[4], acc1[4];
#pragma unroll
  for (int i = 0; i < 4; ++i) { acc0[i] = bias; acc1[i] = bias; }

  for (int cin = 0; cin < 32; ++cin) {
    const float* wp = wts + c * 289 + cin * 9;
    const float w00 = wp[0], w01 = wp[1], w02 = wp[2];
    const float w10 = wp[3], w11 = wp[4], w12 = wp[5];
    const float w20 = wp[6], w21 = wp[7], w22 = wp[8];
    const float* ip = inT + cin * 68;
#pragma unroll
    for (int i = 0; i < 4; ++i) {
      const int kl = sub + 8 * i;
      const float* q = ip + kl * 2;
      const float i00 = q[0], i01 = q[1];
      const float i10 = q[2], i11 = q[3];
      const float i20 = q[4], i21 = q[5];
      acc0[i] = fmaf(i00, w01, acc0[i]); acc0[i] = fmaf(i01, w02, acc0[i]);
      acc0[i] = fmaf(i10, w11, acc0[i]); acc0[i] = fmaf(i11, w12, acc0[i]);
      acc0[i] = fmaf(i20, w21, acc0[i]); acc0[i] = fmaf(i21, w22, acc0[i]);
      acc1[i] = fmaf(i00, w00, acc1[i]); acc1[i] = fmaf(i01, w01, acc1[i]);
      acc1[i] = fmaf(i10, w10, acc1[i]); acc1[i] = fmaf(i11, w11, acc1[i]);
      acc1[i] = fmaf(i20, w20, acc1[i]); acc1[i] = fmaf(i21, w21, acc1[i]);
    }
  }
#pragma unroll
  for (int i = 0; i < 4; ++i) {
    const int k = k0 + sub + 8 * i;
    const size_t o = ((size_t)(b * 64 + br * 32 + c) * KK + k) * 2;
    out[o] = acc0[i];
    out[o + 1] = acc1[i];
  }
}

// ---------------------------------------------------------------- launch
extern "C" void kernel_launch(void* const* d_in, const int* in_sizes, int n_in,
                              void* d_out, int out_size, void* d_ws, size_t ws_size,
                              hipStream_t stream) {
  (void)in_sizes; (void)n_in; (void)out_size; (void)ws_size;
  const float* X   = (const float*)d_in[0];
  const float* S   = (const float*)d_in[1];
  const float* W1x = (const float*)d_in[2];
  const float* W1s = (const float*)d_in[3];
  const float* W2x = (const float*)d_in[4];
  const float* W2s = (const float*)d_in[5];
  const float* Cwx = (const float*)d_in[6];
  const float* Cbx = (const float*)d_in[7];
  const float* Cws = (const float*)d_in[8];
  const float* Cbs = (const float*)d_in[9];
  float* out = (float*)d_out;
  float* ws = (float*)d_ws;

  ushortT* Ehl = (ushortT*)(ws + OFF_EHL);
  ushortT* Ept = (ushortT*)(ws + OFF_ET);
  ushortT* EaT = (ushortT*)(ws + OFF_EAT);
  float*   pb  = ws + OFF_PB;
  float*   pmx = ws + OFF_PMX;
  float*   psm = ws + OFF_PSM;
  float*   pmm = ws + OFF_PMM;

  hipLaunchKernelGGL(prep_kernel, dim3(16, NBATCH, 2), dim3(TPB), 0, stream,
                     X, S, W1x, W1s, Ehl, Ept);
  hipLaunchKernelGGL(passA_kernel, dim3(1024), dim3(TPB), 0, stream,
                     Ehl, pmx, psm);
  hipLaunchKernelGGL(passB_kernel, dim3(1024), dim3(TPB), 0, stream,
                     Ehl, Ept, pmx, psm, pb);
  hipLaunchKernelGGL(reduceB_kernel, dim3(512), dim3(TPB), 0, stream,
                     pb, EaT);
  hipLaunchKernelGGL(mmix_kernel, dim3(128, 2, 4), dim3(TPB), 0, stream,
                     EaT, W2x, W2s, pmm);
  hipLaunchKernelGGL(conv_kernel, dim3(64, NBATCH, 2), dim3(TPB), 0, stream,
                     pmm, X, S, Cwx, Cbx, Cws, Cbs, out);
}

// Round 16
// 110.483 us; speedup vs baseline: 1.0198x; 1.0126x over previous
//
#include <hip/hip_runtime.h>
#include <math.h>

#define TPB 256

static constexpr int LL = 16;
static constexpr int KK = 2048;
static constexpr int NBATCH = 4;
static constexpr int NN = 4096;        // K*B
static constexpr int BBR = 8;          // (branch, batch) combos

// workspace layout in float slots (ws is ~268MB)
static constexpr size_t OFF_EHL = 0;          // 8*4096*32 bf16 = 524288 f
static constexpr size_t OFF_ET  = 524288;     // 8*16*4096 bf16 = 262144 f (n-permuted)
static constexpr size_t OFF_EAT = 819200;     // 8*2*16*2048 bf16 = 262144 f
static constexpr size_t OFF_PMX = 3178496;    // 2*8*4096 f32 = 65536 f
static constexpr size_t OFF_PSM = 3244032;    // 65536 f
static constexpr size_t OFF_PMM = 3309568;    // 4ks*2br*4b*2t*16l*2048j f32 = 2097152 f

typedef unsigned short ushortT;
typedef __attribute__((ext_vector_type(8))) short short8v;
typedef __attribute__((ext_vector_type(4))) float f32x4;
typedef __attribute__((ext_vector_type(16))) float f32x16;

__device__ __forceinline__ ushortT f2bf(float x) {
  union { float f; unsigned int u; } c; c.f = x;
  unsigned int u = c.u;
  return (ushortT)((u + 0x7FFFu + ((u >> 16) & 1u)) >> 16);
}
__device__ __forceinline__ float bf2f(ushortT h) {
  union { unsigned int u; float f; } c; c.u = ((unsigned int)h) << 16;
  return c.f;
}
__device__ __forceinline__ float exp2a(float x) {
  float r; asm("v_exp_f32 %0, %1" : "=v"(r) : "v"(x)); return r;
}

// ---------------------------------------------------------------- prep
// (R8-proven, verbatim.) One branch per blockIdx.z.
__global__ __launch_bounds__(TPB) void prep_kernel(
    const float* __restrict__ X, const float* __restrict__ S,
    const float* __restrict__ W1x, const float* __restrict__ W1s,
    ushortT* __restrict__ Ehl, ushortT* __restrict__ Ept) {
  __shared__ float wsh[256];
  __shared__ ushortT tl[16][272];
  const int tid = threadIdx.x;
  const int br = blockIdx.z;
  wsh[tid] = br ? W1s[tid] : W1x[tid];
  __syncthreads();
  const int n0 = blockIdx.x * 256;
  const int b = blockIdx.y;
  const int n = n0 + tid;
  const float SC = 1.2011224087f;  // sqrt(log2(e))
  const int wq = tid & 31;
  const int slot = (wq < 16) ? ((wq >> 2) * 8 + (wq & 3))
                             : (((wq - 16) >> 2) * 8 + 4 + (wq & 3));
  const int ptid = (tid & ~31) | slot;
  const float* In = br ? X : S;     // Xe uses S, Se uses X (cross-wired)

  float in[16];
#pragma unroll
  for (int l = 0; l < 16; ++l)
    in[l] = In[(size_t)(b * 16 + l) * NN + n];
  float e[16];
#pragma unroll
  for (int m = 0; m < 16; ++m) {
    float a0 = 0.f;
#pragma unroll
    for (int l = 0; l < 16; ++l) a0 = fmaf(in[l], wsh[l * 16 + m], a0);
    e[m] = a0;
  }
  const int bbr = br * 4 + b;
  unsigned int rw[16];
#pragma unroll
  for (int q = 0; q < 16; ++q) rw[q] = 0;
#pragma unroll
  for (int k = 0; k < 16; ++k) {
    const float vs = e[k] * SC;
    ushortT h = f2bf(vs);
    ushortT lo = f2bf(vs - bf2f(h));
    rw[k >> 1] |= ((unsigned int)h) << (16 * (k & 1));
    rw[8 + (k >> 1)] |= ((unsigned int)lo) << (16 * (k & 1));
    tl[k][ptid] = f2bf(e[k]);           // unscaled hi for PV operand
  }
  uint4* dst = (uint4*)(Ehl + ((size_t)bbr * NN + n) * 32);
  dst[0] = make_uint4(rw[0], rw[1], rw[2], rw[3]);
  dst[1] = make_uint4(rw[4], rw[5], rw[6], rw[7]);
  dst[2] = make_uint4(rw[8], rw[9], rw[10], rw[11]);
  dst[3] = make_uint4(rw[12], rw[13], rw[14], rw[15]);
  __syncthreads();
  {
    const int r = tid >> 4, c0 = (tid & 15) * 16;
    const uint4* src = (const uint4*)(&tl[r][c0]);
    uint4* d2 = (uint4*)(Ept + ((size_t)bbr * 16 + r) * NN + n0 + c0);
    d2[0] = src[0];
    d2[1] = src[1];
  }
}

// ---------------------------------------------------------------- pass A (32x32x16 MFMA)
// (R13-proven, verbatim.)
__global__ __launch_bounds__(TPB) void passA_kernel(
    const ushortT* __restrict__ Ehl, float* __restrict__ pmx,
    float* __restrict__ psm) {
  const int bid = blockIdx.x;
  const int bbr = bid & 7;
  const int ms = (bid >> 3) & 1;
  const int n0 = (bid >> 4) * 64;
  const int tid = threadIdx.x;
  const int w = tid >> 6, lane = tid & 63;
  const int lc = lane & 31;
  const int koff = (lane >> 5) * 8;      // k-slot offset for A/B frags
  const ushortT* Eb = Ehl + (size_t)bbr * NN * 32;

  short8v bh[2], bl[2];
#pragma unroll
  for (int s = 0; s < 2; ++s) {
    const ushortT* rp = Eb + (size_t)(n0 + s * 32 + lc) * 32;
    bh[s] = *(const short8v*)(rp + koff);
    bl[s] = *(const short8v*)(rp + 16 + koff);
  }
  float mx[2] = {-INFINITY, -INFINITY};
  float sm[2] = {0.f, 0.f};
  const f32x16 z16 = {0.f, 0.f, 0.f, 0.f, 0.f, 0.f, 0.f, 0.f,
                      0.f, 0.f, 0.f, 0.f, 0.f, 0.f, 0.f, 0.f};
  const ushortT* ap = Eb + (size_t)(ms * 2048 + w * 512 + lc) * 32;
  for (int ch = 0; ch < 16; ++ch) {
    short8v ah = *(const short8v*)(ap + koff);
    short8v al = *(const short8v*)(ap + 16 + koff);
    ap += 32 * 32;
#pragma unroll
    for (int s = 0; s < 2; ++s) {
      f32x16 c = __builtin_amdgcn_mfma_f32_32x32x16_bf16(ah, bh[s], z16, 0, 0, 0);
      c = __builtin_amdgcn_mfma_f32_32x32x16_bf16(al, bh[s], c, 0, 0, 0);
      c = __builtin_amdgcn_mfma_f32_32x32x16_bf16(ah, bl[s], c, 0, 0, 0);
      float t0 = fmaxf(fmaxf(c[0], c[1]), fmaxf(c[2], c[3]));
      float t1 = fmaxf(fmaxf(c[4], c[5]), fmaxf(c[6], c[7]));
      float t2 = fmaxf(fmaxf(c[8], c[9]), fmaxf(c[10], c[11]));
      float t3 = fmaxf(fmaxf(c[12], c[13]), fmaxf(c[14], c[15]));
      float tm = fmaxf(fmaxf(t0, t1), fmaxf(t2, t3));
      if (tm > mx[s] + 30.f) {            // deferred rescale (rare)
        sm[s] *= exp2a(mx[s] - tm);
        mx[s] = tm;
      }
      float e0 = exp2a(c[0] - mx[s]) + exp2a(c[1] - mx[s]);
      float e1 = exp2a(c[2] - mx[s]) + exp2a(c[3] - mx[s]);
      float e2 = exp2a(c[4] - mx[s]) + exp2a(c[5] - mx[s]);
      float e3 = exp2a(c[6] - mx[s]) + exp2a(c[7] - mx[s]);
      float e4 = exp2a(c[8] - mx[s]) + exp2a(c[9] - mx[s]);
      float e5 = exp2a(c[10] - mx[s]) + exp2a(c[11] - mx[s]);
      float e6 = exp2a(c[12] - mx[s]) + exp2a(c[13] - mx[s]);
      float e7 = exp2a(c[14] - mx[s]) + exp2a(c[15] - mx[s]);
      sm[s] += ((e0 + e1) + (e2 + e3)) + ((e4 + e5) + (e6 + e7));
    }
  }
#pragma unroll
  for (int s = 0; s < 2; ++s) {
    float omx = __shfl_xor(mx[s], 32);
    float osm = __shfl_xor(sm[s], 32);
    float nm = fmaxf(mx[s], omx);
    sm[s] = sm[s] * exp2a(mx[s] - nm) + osm * exp2a(omx - nm);
    mx[s] = nm;
  }
  __shared__ float smx[4][2][32], ssm[4][2][32];
  if (lane < 32) {
#pragma unroll
    for (int s = 0; s < 2; ++s) {
      smx[w][s][lc] = mx[s];
      ssm[w][s][lc] = sm[s];
    }
  }
  __syncthreads();
  if (tid < 64) {
    const int s = tid >> 5, col = tid & 31;
    float M = fmaxf(fmaxf(smx[0][s][col], smx[1][s][col]),
                    fmaxf(smx[2][s][col], smx[3][s][col]));
    float Ssum = ssm[0][s][col] * exp2a(smx[0][s][col] - M) +
                 ssm[1][s][col] * exp2a(smx[1][s][col] - M) +
                 ssm[2][s][col] * exp2a(smx[2][s][col] - M) +
                 ssm[3][s][col] * exp2a(smx[3][s][col] - M);
    const size_t o = (size_t)(ms * 8 + bbr) * NN + n0 + s * 32 + col;
    pmx[o] = M;
    psm[o] = Ssum;
  }
}

// ---------------------------------------------------------------- pass B
// UNSPLIT: each block reduces the FULL n=4096 span (4 waves x 1024 n,
// 32 chunks) and writes EaT bf16 directly. reduceB + pb eliminated.
__global__ __launch_bounds__(TPB) void passB_kernel(
    const ushortT* __restrict__ Ehl, const ushortT* __restrict__ Ept,
    const float* __restrict__ pmx, const float* __restrict__ psm,
    ushortT* __restrict__ EaT) {
  const int bid = blockIdx.x;
  const int bbr = bid & 7;
  const int m0 = (bid >> 3) * 64;
  const int tid = threadIdx.x;
  const int w = tid >> 6, lane = tid & 63;
  const int lr = lane & 15, g = lane >> 4;
  const ushortT* Eb = Ehl + (size_t)bbr * NN * 32;
  const ushortT* Tb = Ept + (size_t)bbr * 16 * NN;
  __shared__ float lsb[4096];
  __shared__ float red[4][4][16][17];
  for (int i = tid; i < 4096; i += TPB) {
    const size_t base = (size_t)bbr * NN + i;
    float m0v = pmx[base], m1v = pmx[32768 + base];
    float s0v = psm[base], s1v = psm[32768 + base];
    float M = fmaxf(m0v, m1v);
    float Ssum = s0v * exp2a(m0v - M) + s1v * exp2a(m1v - M);
    lsb[i] = -(M + log2f(fmaxf(Ssum, 1e-38f)));
  }
  __syncthreads();

  const short8v zero8 = {0, 0, 0, 0, 0, 0, 0, 0};
  short8v b1[4], b2[4];
#pragma unroll
  for (int s = 0; s < 4; ++s) {
    const ushortT* rp = Eb + (size_t)(m0 + s * 16 + lr) * 32;
    b1[s] = *(const short8v*)(rp + (g & 1) * 8);
    b2[s] = zero8;
    if (g < 2) b2[s] = *(const short8v*)(rp + 16 + g * 8);
  }
  f32x4 acc[4] = {{0.f, 0.f, 0.f, 0.f}, {0.f, 0.f, 0.f, 0.f},
                  {0.f, 0.f, 0.f, 0.f}, {0.f, 0.f, 0.f, 0.f}};
  const ushortT* ap = Eb + (size_t)(w * 1024 + lr) * 32 + g * 8;
  const ushortT* vp = Tb + (size_t)lr * NN + w * 1024 + g * 8;
  const float* lp = lsb + w * 1024 + g * 4;
#pragma unroll 2
  for (int ch = 0; ch < 32; ++ch) {
    short8v a0 = *(const short8v*)ap;
    short8v a1 = *(const short8v*)(ap + 16 * 32);
    short8v ae = *(const short8v*)vp;
    f32x4 sd0 = *(const f32x4*)lp;          // -lse for rows nb+g*4..+3
    f32x4 sd1 = *(const f32x4*)(lp + 16);   // -lse for rows nb+16+g*4..+3
    ap += 32 * 32; vp += 32; lp += 32;
#pragma unroll
    for (int s = 0; s < 4; ++s) {
      f32x4 c0 = __builtin_amdgcn_mfma_f32_16x16x32_bf16(a0, b1[s], sd0, 0, 0, 0);
      c0 = __builtin_amdgcn_mfma_f32_16x16x32_bf16(a0, b2[s], c0, 0, 0, 0);
      f32x4 c1 = __builtin_amdgcn_mfma_f32_16x16x32_bf16(a1, b1[s], sd1, 0, 0, 0);
      c1 = __builtin_amdgcn_mfma_f32_16x16x32_bf16(a1, b2[s], c1, 0, 0, 0);
      float p0 = exp2a(c0[0]), p1 = exp2a(c0[1]);
      float p2 = exp2a(c0[2]), p3 = exp2a(c0[3]);
      float q0 = exp2a(c1[0]), q1 = exp2a(c1[1]);
      float q2 = exp2a(c1[2]), q3 = exp2a(c1[3]);
      unsigned int u0, u1, u2, u3;
      asm("v_cvt_pk_bf16_f32 %0, %1, %2" : "=v"(u0) : "v"(p0), "v"(p1));
      asm("v_cvt_pk_bf16_f32 %0, %1, %2" : "=v"(u1) : "v"(p2), "v"(p3));
      asm("v_cvt_pk_bf16_f32 %0, %1, %2" : "=v"(u2) : "v"(q0), "v"(q1));
      asm("v_cvt_pk_bf16_f32 %0, %1, %2" : "=v"(u3) : "v"(q2), "v"(q3));
      const uint4 uv = make_uint4(u0, u1, u2, u3);
      const short8v pf = __builtin_bit_cast(short8v, uv);
      acc[s] = __builtin_amdgcn_mfma_f32_16x16x32_bf16(ae, pf, acc[s], 0, 0, 0);
    }
  }
#pragma unroll
  for (int s = 0; s < 4; ++s)
#pragma unroll
    for (int r = 0; r < 4; ++r) red[w][s][g * 4 + r][lr] = acc[s][r];
  __syncthreads();
  for (int o = tid; o < 1024; o += TPB) {
    const int s = o >> 8, l = (o >> 4) & 15, mm = o & 15;
    float v = red[0][s][l][mm] + red[1][s][l][mm] +
              red[2][s][l][mm] + red[3][s][l][mm];
    const int M = m0 + s * 16 + mm;
    EaT[((size_t)(bbr * 2 + (M & 1)) * 16 + l) * (size_t)KK + (M >> 1)] = f2bf(v);
  }
}

// ---------------------------------------------------------------- M-mix (MFMA), k-split x4 -> f32 partials
// (R13-proven, verbatim — deep-prefetch REVERTED to rolling prefetch-1.)
__global__ __launch_bounds__(TPB) void mmix_kernel(
    const ushortT* __restrict__ EaT,
    const float* __restrict__ W2x, const float* __restrict__ W2s,
    float* __restrict__ pmm) {
  const int jt = blockIdx.x;   // 0..127
  const int br = blockIdx.y;   // 0..1
  const int ks = blockIdx.z;   // 0..3 (512-row K slice)
  const float* W2 = br ? W2s : W2x;
  const int j0 = jt * 16;
  const int kb = ks * 512;
  const int tid = threadIdx.x;
  const int w = tid >> 6, lane = tid & 63;
  const int b = w;
  const int lj = tid & 15, kp0 = tid >> 4;
  const int fl = lane & 15, g = lane >> 4;
  __shared__ ushortT bpan[2][16][72];

  const size_t rb0 = ((size_t)(br * 4 + b) * 2 + 0) * 16;
  const size_t rb1 = ((size_t)(br * 4 + b) * 2 + 1) * 16;

  f32x4 acc0 = {0.f, 0.f, 0.f, 0.f};
  f32x4 acc1 = {0.f, 0.f, 0.f, 0.f};

  float r0, r1, r2, r3;
  r0 = W2[(size_t)(kb + 2 * kp0)      * KK + j0 + lj];
  r1 = W2[(size_t)(kb + 2 * kp0 + 1)  * KK + j0 + lj];
  r2 = W2[(size_t)(kb + 2 * kp0 + 32) * KK + j0 + lj];
  r3 = W2[(size_t)(kb + 2 * kp0 + 33) * KK + j0 + lj];

  for (int c = 0; c < 8; ++c) {
    const int cur = c & 1;
    unsigned int u0, u1;
    asm("v_cvt_pk_bf16_f32 %0, %1, %2" : "=v"(u0) : "v"(r0), "v"(r1));
    asm("v_cvt_pk_bf16_f32 %0, %1, %2" : "=v"(u1) : "v"(r2), "v"(r3));
    *(unsigned int*)(&bpan[cur][lj][kp0 * 2]) = u0;
    *(unsigned int*)(&bpan[cur][lj][(kp0 + 16) * 2]) = u1;
    __syncthreads();
    if (c < 7) {
      const int kc = kb + (c + 1) * 64;
      r0 = W2[(size_t)(kc + 2 * kp0)      * KK + j0 + lj];
      r1 = W2[(size_t)(kc + 2 * kp0 + 1)  * KK + j0 + lj];
      r2 = W2[(size_t)(kc + 2 * kp0 + 32) * KK + j0 + lj];
      r3 = W2[(size_t)(kc + 2 * kp0 + 33) * KK + j0 + lj];
    }
#pragma unroll
    for (int s = 0; s < 2; ++s) {
      const int k = kb + c * 64 + s * 32 + g * 8;
      short8v bf = *(const short8v*)(&bpan[cur][fl][s * 32 + g * 8]);
      short8v a0 = *(const short8v*)(EaT + (rb0 + fl) * (size_t)KK + k);
      short8v a1 = *(const short8v*)(EaT + (rb1 + fl) * (size_t)KK + k);
      acc0 = __builtin_amdgcn_mfma_f32_16x16x32_bf16(a0, bf, acc0, 0, 0, 0);
      acc1 = __builtin_amdgcn_mfma_f32_16x16x32_bf16(a1, bf, acc1, 0, 0, 0);
    }
    __syncthreads();
  }

  const int j = j0 + fl;
#pragma unroll
  for (int r = 0; r < 4; ++r) {
    const int l = g * 4 + r;
    const size_t base = ((size_t)(ks * 2 + br) * 4 + b) * 2;
    pmm[((base + 0) * 16 + l) * (size_t)KK + j] = acc0[r];
    pmm[((base + 1) * 16 + l) * (size_t)KK + j] = acc1[r];
  }
}

// ---------------------------------------------------------------- 3x3 SAME conv, H=2048 W=2
// (R13-proven, verbatim.) FUSED mergeM.
__global__ __launch_bounds__(TPB) void conv_kernel(
    const float* __restrict__ pmm,
    const float* __restrict__ X, const float* __restrict__ S,
    const float* __restrict__ Wx, const float* __restrict__ Bx,
    const float* __restrict__ Ws, const float* __restrict__ Bs,
    float* __restrict__ out) {
  const int kt = blockIdx.x;   // 0..63
  const int b = blockIdx.y;
  const int br = blockIdx.z;
  const float* Wt = br ? Ws : Wx;
  const float* Bi = br ? Bs : Bx;
  const float* Inp = br ? S : X;
  __shared__ float inT[32 * 34 * 2];     // [cin][34][2] halo rows
  __shared__ float wts[32 * 289];
  const int tid = threadIdx.x;
  const int k0 = kt * 32;

  for (int f = tid; f < 32 * 288; f += TPB) {
    const int c = f / 288, rem = f % 288;
    wts[c * 289 + rem] = Wt[f];
  }
  for (int f = tid; f < 32 * 34 * 2; f += TPB) {
    const int cin = f / 68, rem = f % 68;
    const int kk = rem >> 1, t = rem & 1;
    const int j = k0 - 1 + kk;
    float v = 0.f;
    if (j >= 0 && j < KK) {
      const int l = cin & 15;
      const float inv = Inp[(size_t)(b * 16 + l) * NN + 2 * j + t];
      if (cin < 16) {
        float sum = 0.f;
#pragma unroll
        for (int ks = 0; ks < 4; ++ks)
          sum += pmm[((((size_t)(ks * 2 + br) * 4 + b) * 2 + t) * 16 + l) *
                         (size_t)KK + j];
        if (br == 0) {
          v = sum * inv;
        } else {
          const float pe = t ? cosf((float)j) : sinf((float)j);
          v = fmaf(sum, inv, pe);
        }
      } else {
        if (br == 0) {
          v = inv;
        } else {
          const float pe = t ? cosf((float)j) : sinf((float)j);
          v = inv + pe;
        }
      }
    }
    inT[f] = v;
  }
  __syncthreads();

  const int c = tid >> 3, sub = tid & 7;
  const float bias = Bi[c];
  float acc0[4], acc1[4];
#pragma unroll
  for (int i = 0; i < 4; ++i) { acc0[i] = bias; acc1[i] = bias; }

  for (int cin = 0; cin < 32; ++cin) {
    const float* wp = wts + c * 289 + cin * 9;
    const float w00 = wp[0], w01 = wp[1], w02 = wp[2];
    const float w10 = wp[3], w11 = wp[4], w12 = wp[5];
    const float w20 = wp[6], w21 = wp[7], w22 = wp[8];
    const float* ip = inT + cin * 68;
#pragma unroll
    for (int i = 0; i < 4; ++i) {
      const int kl = sub + 8 * i;
      const float* q = ip + kl * 2;
      const float i00 = q[0], i01 = q[1];
      const float i10 = q[2], i11 = q[3];
      const float i20 = q[4], i21 = q[5];
      acc0[i] = fmaf(i00, w01, acc0[i]); acc0[i] = fmaf(i01, w02, acc0[i]);
      acc0[i] = fmaf(i10, w11, acc0[i]); acc0[i] = fmaf(i11, w12, acc0[i]);
      acc0[i] = fmaf(i20, w21, acc0[i]); acc0[i] = fmaf(i21, w22, acc0[i]);
      acc1[i] = fmaf(i00, w00, acc1[i]); acc1[i] = fmaf(i01, w01, acc1[i]);
      acc1[i] = fmaf(i10, w10, acc1[i]); acc1[i] = fmaf(i11, w11, acc1[i]);
      acc1[i] = fmaf(i20, w20, acc1[i]); acc1[i] = fmaf(i21, w21, acc1[i]);
    }
  }
#pragma unroll
  for (int i = 0; i < 4; ++i) {
    const int k = k0 + sub + 8 * i;
    const size_t o = ((size_t)(b * 64 + br * 32 + c) * KK + k) * 2;
    out[o] = acc0[i];
    out[o + 1] = acc1[i];
  }
}

// ---------------------------------------------------------------- launch
extern "C" void kernel_launch(void* const* d_in, const int* in_sizes, int n_in,
                              void* d_out, int out_size, void* d_ws, size_t ws_size,
                              hipStream_t stream) {
  (void)in_sizes; (void)n_in; (void)out_size; (void)ws_size;
  const float* X   = (const float*)d_in[0];
  const float* S   = (const float*)d_in[1];
  const float* W1x = (const float*)d_in[2];
  const float* W1s = (const float*)d_in[3];
  const float* W2x = (const float*)d_in[4];
  const float* W2s = (const float*)d_in[5];
  const float* Cwx = (const float*)d_in[6];
  const float* Cbx = (const float*)d_in[7];
  const float* Cws = (const float*)d_in[8];
  const float* Cbs = (const float*)d_in[9];
  float* out = (float*)d_out;
  float* ws = (float*)d_ws;

  ushortT* Ehl = (ushortT*)(ws + OFF_EHL);
  ushortT* Ept = (ushortT*)(ws + OFF_ET);
  ushortT* EaT = (ushortT*)(ws + OFF_EAT);
  float*   pmx = ws + OFF_PMX;
  float*   psm = ws + OFF_PSM;
  float*   pmm = ws + OFF_PMM;

  hipLaunchKernelGGL(prep_kernel, dim3(16, NBATCH, 2), dim3(TPB), 0, stream,
                     X, S, W1x, W1s, Ehl, Ept);
  hipLaunchKernelGGL(passA_kernel, dim3(1024), dim3(TPB), 0, stream,
                     Ehl, pmx, psm);
  hipLaunchKernelGGL(passB_kernel, dim3(512), dim3(TPB), 0, stream,
                     Ehl, Ept, pmx, psm, EaT);
  hipLaunchKernelGGL(mmix_kernel, dim3(128, 2, 4), dim3(TPB), 0, stream,
                     EaT, W2x, W2s, pmm);
  hipLaunchKernelGGL(conv_kernel, dim3(64, NBATCH, 2), dim3(TPB), 0, stream,
                     pmm, X, S, Cwx, Cbx, Cws, Cbs, out);
}

// Round 17
// 108.656 us; speedup vs baseline: 1.0369x; 1.0168x over previous
//
#include <hip/hip_runtime.h>
#include <math.h>

#define TPB 256

static constexpr int LL = 16;
static constexpr int KK = 2048;
static constexpr int NBATCH = 4;
static constexpr int NN = 4096;        // K*B
static constexpr int BBR = 8;          // (branch, batch) combos

// workspace layout in float slots (ws is ~268MB)
static constexpr size_t OFF_EHL = 0;          // 8*4096*32 bf16 = 524288 f
static constexpr size_t OFF_ET  = 524288;     // 8*16*4096 bf16 = 262144 f (n-permuted)
static constexpr size_t OFF_EAT = 819200;     // 8*2*16*2048 bf16 = 262144 f
static constexpr size_t OFF_PB  = 2129920;    // 2*8*16*4096 f32 = 1048576 f
static constexpr size_t OFF_PMX = 3178496;    // 2*8*4096 f32 = 65536 f
static constexpr size_t OFF_PSM = 3244032;    // 65536 f
static constexpr size_t OFF_PMM = 3309568;    // 4ks*2br*4b*2t*16l*2048j f32 = 2097152 f

typedef unsigned short ushortT;
typedef __attribute__((ext_vector_type(8))) short short8v;
typedef __attribute__((ext_vector_type(4))) float f32x4;
typedef __attribute__((ext_vector_type(16))) float f32x16;

__device__ __forceinline__ ushortT f2bf(float x) {
  union { float f; unsigned int u; } c; c.f = x;
  unsigned int u = c.u;
  return (ushortT)((u + 0x7FFFu + ((u >> 16) & 1u)) >> 16);
}
__device__ __forceinline__ float bf2f(ushortT h) {
  union { unsigned int u; float f; } c; c.u = ((unsigned int)h) << 16;
  return c.f;
}
__device__ __forceinline__ float exp2a(float x) {
  float r; asm("v_exp_f32 %0, %1" : "=v"(r) : "v"(x)); return r;
}

// ---------------------------------------------------------------- prep
// (R8-proven, verbatim.) One branch per blockIdx.z.
__global__ __launch_bounds__(TPB) void prep_kernel(
    const float* __restrict__ X, const float* __restrict__ S,
    const float* __restrict__ W1x, const float* __restrict__ W1s,
    ushortT* __restrict__ Ehl, ushortT* __restrict__ Ept) {
  __shared__ float wsh[256];
  __shared__ ushortT tl[16][272];
  const int tid = threadIdx.x;
  const int br = blockIdx.z;
  wsh[tid] = br ? W1s[tid] : W1x[tid];
  __syncthreads();
  const int n0 = blockIdx.x * 256;
  const int b = blockIdx.y;
  const int n = n0 + tid;
  const float SC = 1.2011224087f;  // sqrt(log2(e))
  const int wq = tid & 31;
  const int slot = (wq < 16) ? ((wq >> 2) * 8 + (wq & 3))
                             : (((wq - 16) >> 2) * 8 + 4 + (wq & 3));
  const int ptid = (tid & ~31) | slot;
  const float* In = br ? X : S;     // Xe uses S, Se uses X (cross-wired)

  float in[16];
#pragma unroll
  for (int l = 0; l < 16; ++l)
    in[l] = In[(size_t)(b * 16 + l) * NN + n];
  float e[16];
#pragma unroll
  for (int m = 0; m < 16; ++m) {
    float a0 = 0.f;
#pragma unroll
    for (int l = 0; l < 16; ++l) a0 = fmaf(in[l], wsh[l * 16 + m], a0);
    e[m] = a0;
  }
  const int bbr = br * 4 + b;
  unsigned int rw[16];
#pragma unroll
  for (int q = 0; q < 16; ++q) rw[q] = 0;
#pragma unroll
  for (int k = 0; k < 16; ++k) {
    const float vs = e[k] * SC;
    ushortT h = f2bf(vs);
    ushortT lo = f2bf(vs - bf2f(h));
    rw[k >> 1] |= ((unsigned int)h) << (16 * (k & 1));
    rw[8 + (k >> 1)] |= ((unsigned int)lo) << (16 * (k & 1));
    tl[k][ptid] = f2bf(e[k]);           // unscaled hi for PV operand
  }
  uint4* dst = (uint4*)(Ehl + ((size_t)bbr * NN + n) * 32);
  dst[0] = make_uint4(rw[0], rw[1], rw[2], rw[3]);
  dst[1] = make_uint4(rw[4], rw[5], rw[6], rw[7]);
  dst[2] = make_uint4(rw[8], rw[9], rw[10], rw[11]);
  dst[3] = make_uint4(rw[12], rw[13], rw[14], rw[15]);
  __syncthreads();
  {
    const int r = tid >> 4, c0 = (tid & 15) * 16;
    const uint4* src = (const uint4*)(&tl[r][c0]);
    uint4* d2 = (uint4*)(Ept + ((size_t)bbr * 16 + r) * NN + n0 + c0);
    d2[0] = src[0];
    d2[1] = src[1];
  }
}

// ---------------------------------------------------------------- pass A (32x32x16 MFMA)
// (R13-proven, verbatim.)
__global__ __launch_bounds__(TPB) void passA_kernel(
    const ushortT* __restrict__ Ehl, float* __restrict__ pmx,
    float* __restrict__ psm) {
  const int bid = blockIdx.x;
  const int bbr = bid & 7;
  const int ms = (bid >> 3) & 1;
  const int n0 = (bid >> 4) * 64;
  const int tid = threadIdx.x;
  const int w = tid >> 6, lane = tid & 63;
  const int lc = lane & 31;
  const int koff = (lane >> 5) * 8;      // k-slot offset for A/B frags
  const ushortT* Eb = Ehl + (size_t)bbr * NN * 32;

  short8v bh[2], bl[2];
#pragma unroll
  for (int s = 0; s < 2; ++s) {
    const ushortT* rp = Eb + (size_t)(n0 + s * 32 + lc) * 32;
    bh[s] = *(const short8v*)(rp + koff);
    bl[s] = *(const short8v*)(rp + 16 + koff);
  }
  float mx[2] = {-INFINITY, -INFINITY};
  float sm[2] = {0.f, 0.f};
  const f32x16 z16 = {0.f, 0.f, 0.f, 0.f, 0.f, 0.f, 0.f, 0.f,
                      0.f, 0.f, 0.f, 0.f, 0.f, 0.f, 0.f, 0.f};
  const ushortT* ap = Eb + (size_t)(ms * 2048 + w * 512 + lc) * 32;
  for (int ch = 0; ch < 16; ++ch) {
    short8v ah = *(const short8v*)(ap + koff);
    short8v al = *(const short8v*)(ap + 16 + koff);
    ap += 32 * 32;
#pragma unroll
    for (int s = 0; s < 2; ++s) {
      f32x16 c = __builtin_amdgcn_mfma_f32_32x32x16_bf16(ah, bh[s], z16, 0, 0, 0);
      c = __builtin_amdgcn_mfma_f32_32x32x16_bf16(al, bh[s], c, 0, 0, 0);
      c = __builtin_amdgcn_mfma_f32_32x32x16_bf16(ah, bl[s], c, 0, 0, 0);
      float t0 = fmaxf(fmaxf(c[0], c[1]), fmaxf(c[2], c[3]));
      float t1 = fmaxf(fmaxf(c[4], c[5]), fmaxf(c[6], c[7]));
      float t2 = fmaxf(fmaxf(c[8], c[9]), fmaxf(c[10], c[11]));
      float t3 = fmaxf(fmaxf(c[12], c[13]), fmaxf(c[14], c[15]));
      float tm = fmaxf(fmaxf(t0, t1), fmaxf(t2, t3));
      if (tm > mx[s] + 30.f) {            // deferred rescale (rare)
        sm[s] *= exp2a(mx[s] - tm);
        mx[s] = tm;
      }
      float e0 = exp2a(c[0] - mx[s]) + exp2a(c[1] - mx[s]);
      float e1 = exp2a(c[2] - mx[s]) + exp2a(c[3] - mx[s]);
      float e2 = exp2a(c[4] - mx[s]) + exp2a(c[5] - mx[s]);
      float e3 = exp2a(c[6] - mx[s]) + exp2a(c[7] - mx[s]);
      float e4 = exp2a(c[8] - mx[s]) + exp2a(c[9] - mx[s]);
      float e5 = exp2a(c[10] - mx[s]) + exp2a(c[11] - mx[s]);
      float e6 = exp2a(c[12] - mx[s]) + exp2a(c[13] - mx[s]);
      float e7 = exp2a(c[14] - mx[s]) + exp2a(c[15] - mx[s]);
      sm[s] += ((e0 + e1) + (e2 + e3)) + ((e4 + e5) + (e6 + e7));
    }
  }
#pragma unroll
  for (int s = 0; s < 2; ++s) {
    float omx = __shfl_xor(mx[s], 32);
    float osm = __shfl_xor(sm[s], 32);
    float nm = fmaxf(mx[s], omx);
    sm[s] = sm[s] * exp2a(mx[s] - nm) + osm * exp2a(omx - nm);
    mx[s] = nm;
  }
  __shared__ float smx[4][2][32], ssm[4][2][32];
  if (lane < 32) {
#pragma unroll
    for (int s = 0; s < 2; ++s) {
      smx[w][s][lc] = mx[s];
      ssm[w][s][lc] = sm[s];
    }
  }
  __syncthreads();
  if (tid < 64) {
    const int s = tid >> 5, col = tid & 31;
    float M = fmaxf(fmaxf(smx[0][s][col], smx[1][s][col]),
                    fmaxf(smx[2][s][col], smx[3][s][col]));
    float Ssum = ssm[0][s][col] * exp2a(smx[0][s][col] - M) +
                 ssm[1][s][col] * exp2a(smx[1][s][col] - M) +
                 ssm[2][s][col] * exp2a(smx[2][s][col] - M) +
                 ssm[3][s][col] * exp2a(smx[3][s][col] - M);
    const size_t o = (size_t)(ms * 8 + bbr) * NN + n0 + s * 32 + col;
    pmx[o] = M;
    psm[o] = Ssum;
  }
}

// ---------------------------------------------------------------- pass B
// (R12/R13-proven, verbatim.) FUSED reduceA prologue; ns-split; 64-m tile.
__global__ __launch_bounds__(TPB) void passB_kernel(
    const ushortT* __restrict__ Ehl, const ushortT* __restrict__ Ept,
    const float* __restrict__ pmx, const float* __restrict__ psm,
    float* __restrict__ pb) {
  const int bid = blockIdx.x;
  const int bbr = bid & 7;
  const int ns = (bid >> 3) & 1;
  const int m0 = (bid >> 4) * 64;
  const int tid = threadIdx.x;
  const int w = tid >> 6, lane = tid & 63;
  const int lr = lane & 15, g = lane >> 4;
  const ushortT* Eb = Ehl + (size_t)bbr * NN * 32;
  const ushortT* Tb = Ept + (size_t)bbr * 16 * NN;
  __shared__ float lsb[2048];
  __shared__ float red[4][4][16][17];
  for (int i = tid; i < 2048; i += TPB) {
    const size_t base = (size_t)bbr * NN + ns * 2048 + i;
    float m0v = pmx[base], m1v = pmx[32768 + base];
    float s0v = psm[base], s1v = psm[32768 + base];
    float M = fmaxf(m0v, m1v);
    float Ssum = s0v * exp2a(m0v - M) + s1v * exp2a(m1v - M);
    lsb[i] = -(M + log2f(fmaxf(Ssum, 1e-38f)));
  }
  __syncthreads();

  const short8v zero8 = {0, 0, 0, 0, 0, 0, 0, 0};
  short8v b1[4], b2[4];
#pragma unroll
  for (int s = 0; s < 4; ++s) {
    const ushortT* rp = Eb + (size_t)(m0 + s * 16 + lr) * 32;
    b1[s] = *(const short8v*)(rp + (g & 1) * 8);
    b2[s] = zero8;
    if (g < 2) b2[s] = *(const short8v*)(rp + 16 + g * 8);
  }
  f32x4 acc[4] = {{0.f, 0.f, 0.f, 0.f}, {0.f, 0.f, 0.f, 0.f},
                  {0.f, 0.f, 0.f, 0.f}, {0.f, 0.f, 0.f, 0.f}};
  const ushortT* ap = Eb + (size_t)(ns * 2048 + w * 512 + lr) * 32 + g * 8;
  const ushortT* vp = Tb + (size_t)lr * NN + ns * 2048 + w * 512 + g * 8;
  const float* lp = lsb + w * 512 + g * 4;
#pragma unroll 2
  for (int ch = 0; ch < 16; ++ch) {
    short8v a0 = *(const short8v*)ap;
    short8v a1 = *(const short8v*)(ap + 16 * 32);
    short8v ae = *(const short8v*)vp;
    f32x4 sd0 = *(const f32x4*)lp;          // -lse for rows nb+g*4..+3
    f32x4 sd1 = *(const f32x4*)(lp + 16);   // -lse for rows nb+16+g*4..+3
    ap += 32 * 32; vp += 32; lp += 32;
#pragma unroll
    for (int s = 0; s < 4; ++s) {
      f32x4 c0 = __builtin_amdgcn_mfma_f32_16x16x32_bf16(a0, b1[s], sd0, 0, 0, 0);
      c0 = __builtin_amdgcn_mfma_f32_16x16x32_bf16(a0, b2[s], c0, 0, 0, 0);
      f32x4 c1 = __builtin_amdgcn_mfma_f32_16x16x32_bf16(a1, b1[s], sd1, 0, 0, 0);
      c1 = __builtin_amdgcn_mfma_f32_16x16x32_bf16(a1, b2[s], c1, 0, 0, 0);
      float p0 = exp2a(c0[0]), p1 = exp2a(c0[1]);
      float p2 = exp2a(c0[2]), p3 = exp2a(c0[3]);
      float q0 = exp2a(c1[0]), q1 = exp2a(c1[1]);
      float q2 = exp2a(c1[2]), q3 = exp2a(c1[3]);
      unsigned int u0, u1, u2, u3;
      asm("v_cvt_pk_bf16_f32 %0, %1, %2" : "=v"(u0) : "v"(p0), "v"(p1));
      asm("v_cvt_pk_bf16_f32 %0, %1, %2" : "=v"(u1) : "v"(p2), "v"(p3));
      asm("v_cvt_pk_bf16_f32 %0, %1, %2" : "=v"(u2) : "v"(q0), "v"(q1));
      asm("v_cvt_pk_bf16_f32 %0, %1, %2" : "=v"(u3) : "v"(q2), "v"(q3));
      const uint4 uv = make_uint4(u0, u1, u2, u3);
      const short8v pf = __builtin_bit_cast(short8v, uv);
      acc[s] = __builtin_amdgcn_mfma_f32_16x16x32_bf16(ae, pf, acc[s], 0, 0, 0);
    }
  }
#pragma unroll
  for (int s = 0; s < 4; ++s)
#pragma unroll
    for (int r = 0; r < 4; ++r) red[w][s][g * 4 + r][lr] = acc[s][r];
  __syncthreads();
  for (int o = tid; o < 1024; o += TPB) {
    const int s = o >> 8, l = (o >> 4) & 15, mm = o & 15;
    float v = red[0][s][l][mm] + red[1][s][l][mm] +
              red[2][s][l][mm] + red[3][s][l][mm];
    pb[((size_t)(ns * 8 + bbr) * 16 + l) * NN + m0 + s * 16 + mm] = v;
  }
}

// ---------------------------------------------------------------- reduce B
// (R13-proven, verbatim.)
__global__ __launch_bounds__(TPB) void reduceB_kernel(
    const float* __restrict__ pb, ushortT* __restrict__ EaT) {
  const int gidx = blockIdx.x * TPB + threadIdx.x;   // 0..131071
  const int r = gidx >> 10;                          // bbr*16 + l
  const int j4 = gidx & 1023;
  const float4 p0 = *(const float4*)(pb + (size_t)r * NN + j4 * 4);
  const float4 p1 = *(const float4*)(pb + (size_t)(128 + r) * NN + j4 * 4);
  const float v0 = p0.x + p1.x, v1 = p0.y + p1.y;
  const float v2 = p0.z + p1.z, v3 = p0.w + p1.w;
  const int bbr = r >> 4, l = r & 15;
  unsigned int ue, uo;
  asm("v_cvt_pk_bf16_f32 %0, %1, %2" : "=v"(ue) : "v"(v0), "v"(v2));
  asm("v_cvt_pk_bf16_f32 %0, %1, %2" : "=v"(uo) : "v"(v1), "v"(v3));
  *(unsigned int*)(EaT + ((size_t)(bbr * 2 + 0) * 16 + l) * KK + j4 * 2) = ue;
  *(unsigned int*)(EaT + ((size_t)(bbr * 2 + 1) * 16 + l) * KK + j4 * 2) = uo;
}

// ---------------------------------------------------------------- M-mix (MFMA), k-split x4 -> f32 partials
// (R13-proven, verbatim — rolling prefetch-1.)
__global__ __launch_bounds__(TPB) void mmix_kernel(
    const ushortT* __restrict__ EaT,
    const float* __restrict__ W2x, const float* __restrict__ W2s,
    float* __restrict__ pmm) {
  const int jt = blockIdx.x;   // 0..127
  const int br = blockIdx.y;   // 0..1
  const int ks = blockIdx.z;   // 0..3 (512-row K slice)
  const float* W2 = br ? W2s : W2x;
  const int j0 = jt * 16;
  const int kb = ks * 512;
  const int tid = threadIdx.x;
  const int w = tid >> 6, lane = tid & 63;
  const int b = w;
  const int lj = tid & 15, kp0 = tid >> 4;
  const int fl = lane & 15, g = lane >> 4;
  __shared__ ushortT bpan[2][16][72];

  const size_t rb0 = ((size_t)(br * 4 + b) * 2 + 0) * 16;
  const size_t rb1 = ((size_t)(br * 4 + b) * 2 + 1) * 16;

  f32x4 acc0 = {0.f, 0.f, 0.f, 0.f};
  f32x4 acc1 = {0.f, 0.f, 0.f, 0.f};

  float r0, r1, r2, r3;
  r0 = W2[(size_t)(kb + 2 * kp0)      * KK + j0 + lj];
  r1 = W2[(size_t)(kb + 2 * kp0 + 1)  * KK + j0 + lj];
  r2 = W2[(size_t)(kb + 2 * kp0 + 32) * KK + j0 + lj];
  r3 = W2[(size_t)(kb + 2 * kp0 + 33) * KK + j0 + lj];

  for (int c = 0; c < 8; ++c) {
    const int cur = c & 1;
    unsigned int u0, u1;
    asm("v_cvt_pk_bf16_f32 %0, %1, %2" : "=v"(u0) : "v"(r0), "v"(r1));
    asm("v_cvt_pk_bf16_f32 %0, %1, %2" : "=v"(u1) : "v"(r2), "v"(r3));
    *(unsigned int*)(&bpan[cur][lj][kp0 * 2]) = u0;
    *(unsigned int*)(&bpan[cur][lj][(kp0 + 16) * 2]) = u1;
    __syncthreads();
    if (c < 7) {
      const int kc = kb + (c + 1) * 64;
      r0 = W2[(size_t)(kc + 2 * kp0)      * KK + j0 + lj];
      r1 = W2[(size_t)(kc + 2 * kp0 + 1)  * KK + j0 + lj];
      r2 = W2[(size_t)(kc + 2 * kp0 + 32) * KK + j0 + lj];
      r3 = W2[(size_t)(kc + 2 * kp0 + 33) * KK + j0 + lj];
    }
#pragma unroll
    for (int s = 0; s < 2; ++s) {
      const int k = kb + c * 64 + s * 32 + g * 8;
      short8v bf = *(const short8v*)(&bpan[cur][fl][s * 32 + g * 8]);
      short8v a0 = *(const short8v*)(EaT + (rb0 + fl) * (size_t)KK + k);
      short8v a1 = *(const short8v*)(EaT + (rb1 + fl) * (size_t)KK + k);
      acc0 = __builtin_amdgcn_mfma_f32_16x16x32_bf16(a0, bf, acc0, 0, 0, 0);
      acc1 = __builtin_amdgcn_mfma_f32_16x16x32_bf16(a1, bf, acc1, 0, 0, 0);
    }
    __syncthreads();
  }

  const int j = j0 + fl;
#pragma unroll
  for (int r = 0; r < 4; ++r) {
    const int l = g * 4 + r;
    const size_t base = ((size_t)(ks * 2 + br) * 4 + b) * 2;
    pmm[((base + 0) * 16 + l) * (size_t)KK + j] = acc0[r];
    pmm[((base + 1) * 16 + l) * (size_t)KK + j] = acc1[r];
  }
}

// ---------------------------------------------------------------- 3x3 SAME conv, H=2048 W=2
// (R13-proven, verbatim.) FUSED mergeM: inT from pmm partial sums + X/S + PE.
__global__ __launch_bounds__(TPB) void conv_kernel(
    const float* __restrict__ pmm,
    const float* __restrict__ X, const float* __restrict__ S,
    const float* __restrict__ Wx, const float* __restrict__ Bx,
    const float* __restrict__ Ws, const float* __restrict__ Bs,
    float* __restrict__ out) {
  const int kt = blockIdx.x;   // 0..63
  const int b = blockIdx.y;
  const int br = blockIdx.z;
  const float* Wt = br ? Ws : Wx;
  const float* Bi = br ? Bs : Bx;
  const float* Inp = br ? S : X;
  __shared__ float inT[32 * 34 * 2];     // [cin][34][2] halo rows
  __shared__ float wts[32 * 289];
  const int tid = threadIdx.x;
  const int k0 = kt * 32;

  for (int f = tid; f < 32 * 288; f += TPB) {
    const int c = f / 288, rem = f % 288;
    wts[c * 289 + rem] = Wt[f];
  }
  for (int f = tid; f < 32 * 34 * 2; f += TPB) {
    const int cin = f / 68, rem = f % 68;
    const int kk = rem >> 1, t = rem & 1;
    const int j = k0 - 1 + kk;
    float v = 0.f;
    if (j >= 0 && j < KK) {
      const int l = cin & 15;
      const float inv = Inp[(size_t)(b * 16 + l) * NN + 2 * j + t];
      if (cin < 16) {
        float sum = 0.f;
#pragma unroll
        for (int ks = 0; ks < 4; ++ks)
          sum += pmm[((((size_t)(ks * 2 + br) * 4 + b) * 2 + t) * 16 + l) *
                         (size_t)KK + j];
        if (br == 0) {
          v = sum * inv;
        } else {
          const float pe = t ? cosf((float)j) : sinf((float)j);
          v = fmaf(sum, inv, pe);
        }
      } else {
        if (br == 0) {
          v = inv;
        } else {
          const float pe = t ? cosf((float)j) : sinf((float)j);
          v = inv + pe;
        }
      }
    }
    inT[f] = v;
  }
  __syncthreads();

  const int c = tid >> 3, sub = tid & 7;
  const float bias = Bi[c];
  float acc0[4], acc1[4];
#pragma unroll
  for (int i = 0; i < 4; ++i) { acc0[i] = bias; acc1[i] = bias; }

  for (int cin = 0; cin < 32; ++cin) {
    const float* wp = wts + c * 289 + cin * 9;
    const float w00 = wp[0], w01 = wp[1], w02 = wp[2];
    const float w10 = wp[3], w11 = wp[4], w12 = wp[5];
    const float w20 = wp[6], w21 = wp[7], w22 = wp[8];
    const float* ip = inT + cin * 68;
#pragma unroll
    for (int i = 0; i < 4; ++i) {
      const int kl = sub + 8 * i;
      const float* q = ip + kl * 2;
      const float i00 = q[0], i01 = q[1];
      const float i10 = q[2], i11 = q[3];
      const float i20 = q[4], i21 = q[5];
      acc0[i] = fmaf(i00, w01, acc0[i]); acc0[i] = fmaf(i01, w02, acc0[i]);
      acc0[i] = fmaf(i10, w11, acc0[i]); acc0[i] = fmaf(i11, w12, acc0[i]);
      acc0[i] = fmaf(i20, w21, acc0[i]); acc0[i] = fmaf(i21, w22, acc0[i]);
      acc1[i] = fmaf(i00, w00, acc1[i]); acc1[i] = fmaf(i01, w01, acc1[i]);
      acc1[i] = fmaf(i10, w10, acc1[i]); acc1[i] = fmaf(i11, w11, acc1[i]);
      acc1[i] = fmaf(i20, w20, acc1[i]); acc1[i] = fmaf(i21, w21, acc1[i]);
    }
  }
#pragma unroll
  for (int i = 0; i < 4; ++i) {
    const int k = k0 + sub + 8 * i;
    const size_t o = ((size_t)(b * 64 + br * 32 + c) * KK + k) * 2;
    out[o] = acc0[i];
    out[o + 1] = acc1[i];
  }
}

// ---------------------------------------------------------------- launch
extern "C" void kernel_launch(void* const* d_in, const int* in_sizes, int n_in,
                              void* d_out, int out_size, void* d_ws, size_t ws_size,
                              hipStream_t stream) {
  (void)in_sizes; (void)n_in; (void)out_size; (void)ws_size;
  const float* X   = (const float*)d_in[0];
  const float* S   = (const float*)d_in[1];
  const float* W1x = (const float*)d_in[2];
  const float* W1s = (const float*)d_in[3];
  const float* W2x = (const float*)d_in[4];
  const float* W2s = (const float*)d_in[5];
  const float* Cwx = (const float*)d_in[6];
  const float* Cbx = (const float*)d_in[7];
  const float* Cws = (const float*)d_in[8];
  const float* Cbs = (const float*)d_in[9];
  float* out = (float*)d_out;
  float* ws = (float*)d_ws;

  ushortT* Ehl = (ushortT*)(ws + OFF_EHL);
  ushortT* Ept = (ushortT*)(ws + OFF_ET);
  ushortT* EaT = (ushortT*)(ws + OFF_EAT);
  float*   pb  = ws + OFF_PB;
  float*   pmx = ws + OFF_PMX;
  float*   psm = ws + OFF_PSM;
  float*   pmm = ws + OFF_PMM;

  hipLaunchKernelGGL(prep_kernel, dim3(16, NBATCH, 2), dim3(TPB), 0, stream,
                     X, S, W1x, W1s, Ehl, Ept);
  hipLaunchKernelGGL(passA_kernel, dim3(1024), dim3(TPB), 0, stream,
                     Ehl, pmx, psm);
  hipLaunchKernelGGL(passB_kernel, dim3(1024), dim3(TPB), 0, stream,
                     Ehl, Ept, pmx, psm, pb);
  hipLaunchKernelGGL(reduceB_kernel, dim3(512), dim3(TPB), 0, stream,
                     pb, EaT);
  hipLaunchKernelGGL(mmix_kernel, dim3(128, 2, 4), dim3(TPB), 0, stream,
                     EaT, W2x, W2s, pmm);
  hipLaunchKernelGGL(conv_kernel, dim3(64, NBATCH, 2), dim3(TPB), 0, stream,
                     pmm, X, S, Cwx, Cbx, Cws, Cbs, out);
}

// Round 18
// 107.409 us; speedup vs baseline: 1.0490x; 1.0116x over previous
//
#include <hip/hip_runtime.h>
#include <math.h>

#define TPB 256

static constexpr int LL = 16;
static constexpr int KK = 2048;
static constexpr int NBATCH = 4;
static constexpr int NN = 4096;        // K*B
static constexpr int BBR = 8;          // (branch, batch) combos

// workspace layout in float slots (ws is ~268MB)
static constexpr size_t OFF_EHL = 0;          // 8*4096*32 bf16 = 524288 f
static constexpr size_t OFF_ET  = 524288;     // 8*16*4096 bf16 = 262144 f (n-permuted)
static constexpr size_t OFF_EAT = 819200;     // 8*2*16*2048 bf16 = 262144 f
static constexpr size_t OFF_PB  = 2129920;    // 2*8*16*4096 f32 = 1048576 f
static constexpr size_t OFF_PMX = 3178496;    // 2*8*4096 f32 = 65536 f
static constexpr size_t OFF_PSM = 3244032;    // 65536 f
static constexpr size_t OFF_PMM = 3309568;    // 4ks*2br*4b*2t*16l*2048j bf16 = 1048576 f-slots used as u16
typedef unsigned short ushortT;
typedef __attribute__((ext_vector_type(8))) short short8v;
typedef __attribute__((ext_vector_type(4))) float f32x4;
typedef __attribute__((ext_vector_type(16))) float f32x16;

__device__ __forceinline__ ushortT f2bf(float x) {
  union { float f; unsigned int u; } c; c.f = x;
  unsigned int u = c.u;
  return (ushortT)((u + 0x7FFFu + ((u >> 16) & 1u)) >> 16);
}
__device__ __forceinline__ float bf2f(ushortT h) {
  union { unsigned int u; float f; } c; c.u = ((unsigned int)h) << 16;
  return c.f;
}
__device__ __forceinline__ float exp2a(float x) {
  float r; asm("v_exp_f32 %0, %1" : "=v"(r) : "v"(x)); return r;
}

// ---------------------------------------------------------------- prep
// (R8-proven, verbatim.) One branch per blockIdx.z.
__global__ __launch_bounds__(TPB) void prep_kernel(
    const float* __restrict__ X, const float* __restrict__ S,
    const float* __restrict__ W1x, const float* __restrict__ W1s,
    ushortT* __restrict__ Ehl, ushortT* __restrict__ Ept) {
  __shared__ float wsh[256];
  __shared__ ushortT tl[16][272];
  const int tid = threadIdx.x;
  const int br = blockIdx.z;
  wsh[tid] = br ? W1s[tid] : W1x[tid];
  __syncthreads();
  const int n0 = blockIdx.x * 256;
  const int b = blockIdx.y;
  const int n = n0 + tid;
  const float SC = 1.2011224087f;  // sqrt(log2(e))
  const int wq = tid & 31;
  const int slot = (wq < 16) ? ((wq >> 2) * 8 + (wq & 3))
                             : (((wq - 16) >> 2) * 8 + 4 + (wq & 3));
  const int ptid = (tid & ~31) | slot;
  const float* In = br ? X : S;     // Xe uses S, Se uses X (cross-wired)

  float in[16];
#pragma unroll
  for (int l = 0; l < 16; ++l)
    in[l] = In[(size_t)(b * 16 + l) * NN + n];
  float e[16];
#pragma unroll
  for (int m = 0; m < 16; ++m) {
    float a0 = 0.f;
#pragma unroll
    for (int l = 0; l < 16; ++l) a0 = fmaf(in[l], wsh[l * 16 + m], a0);
    e[m] = a0;
  }
  const int bbr = br * 4 + b;
  unsigned int rw[16];
#pragma unroll
  for (int q = 0; q < 16; ++q) rw[q] = 0;
#pragma unroll
  for (int k = 0; k < 16; ++k) {
    const float vs = e[k] * SC;
    ushortT h = f2bf(vs);
    ushortT lo = f2bf(vs - bf2f(h));
    rw[k >> 1] |= ((unsigned int)h) << (16 * (k & 1));
    rw[8 + (k >> 1)] |= ((unsigned int)lo) << (16 * (k & 1));
    tl[k][ptid] = f2bf(e[k]);           // unscaled hi for PV operand
  }
  uint4* dst = (uint4*)(Ehl + ((size_t)bbr * NN + n) * 32);
  dst[0] = make_uint4(rw[0], rw[1], rw[2], rw[3]);
  dst[1] = make_uint4(rw[4], rw[5], rw[6], rw[7]);
  dst[2] = make_uint4(rw[8], rw[9], rw[10], rw[11]);
  dst[3] = make_uint4(rw[12], rw[13], rw[14], rw[15]);
  __syncthreads();
  {
    const int r = tid >> 4, c0 = (tid & 15) * 16;
    const uint4* src = (const uint4*)(&tl[r][c0]);
    uint4* d2 = (uint4*)(Ept + ((size_t)bbr * 16 + r) * NN + n0 + c0);
    d2[0] = src[0];
    d2[1] = src[1];
  }
}

// ---------------------------------------------------------------- pass A (32x32x16 MFMA)
// (R13-proven, verbatim.)
__global__ __launch_bounds__(TPB) void passA_kernel(
    const ushortT* __restrict__ Ehl, float* __restrict__ pmx,
    float* __restrict__ psm) {
  const int bid = blockIdx.x;
  const int bbr = bid & 7;
  const int ms = (bid >> 3) & 1;
  const int n0 = (bid >> 4) * 64;
  const int tid = threadIdx.x;
  const int w = tid >> 6, lane = tid & 63;
  const int lc = lane & 31;
  const int koff = (lane >> 5) * 8;      // k-slot offset for A/B frags
  const ushortT* Eb = Ehl + (size_t)bbr * NN * 32;

  short8v bh[2], bl[2];
#pragma unroll
  for (int s = 0; s < 2; ++s) {
    const ushortT* rp = Eb + (size_t)(n0 + s * 32 + lc) * 32;
    bh[s] = *(const short8v*)(rp + koff);
    bl[s] = *(const short8v*)(rp + 16 + koff);
  }
  float mx[2] = {-INFINITY, -INFINITY};
  float sm[2] = {0.f, 0.f};
  const f32x16 z16 = {0.f, 0.f, 0.f, 0.f, 0.f, 0.f, 0.f, 0.f,
                      0.f, 0.f, 0.f, 0.f, 0.f, 0.f, 0.f, 0.f};
  const ushortT* ap = Eb + (size_t)(ms * 2048 + w * 512 + lc) * 32;
  for (int ch = 0; ch < 16; ++ch) {
    short8v ah = *(const short8v*)(ap + koff);
    short8v al = *(const short8v*)(ap + 16 + koff);
    ap += 32 * 32;
#pragma unroll
    for (int s = 0; s < 2; ++s) {
      f32x16 c = __builtin_amdgcn_mfma_f32_32x32x16_bf16(ah, bh[s], z16, 0, 0, 0);
      c = __builtin_amdgcn_mfma_f32_32x32x16_bf16(al, bh[s], c, 0, 0, 0);
      c = __builtin_amdgcn_mfma_f32_32x32x16_bf16(ah, bl[s], c, 0, 0, 0);
      float t0 = fmaxf(fmaxf(c[0], c[1]), fmaxf(c[2], c[3]));
      float t1 = fmaxf(fmaxf(c[4], c[5]), fmaxf(c[6], c[7]));
      float t2 = fmaxf(fmaxf(c[8], c[9]), fmaxf(c[10], c[11]));
      float t3 = fmaxf(fmaxf(c[12], c[13]), fmaxf(c[14], c[15]));
      float tm = fmaxf(fmaxf(t0, t1), fmaxf(t2, t3));
      if (tm > mx[s] + 30.f) {            // deferred rescale (rare)
        sm[s] *= exp2a(mx[s] - tm);
        mx[s] = tm;
      }
      float e0 = exp2a(c[0] - mx[s]) + exp2a(c[1] - mx[s]);
      float e1 = exp2a(c[2] - mx[s]) + exp2a(c[3] - mx[s]);
      float e2 = exp2a(c[4] - mx[s]) + exp2a(c[5] - mx[s]);
      float e3 = exp2a(c[6] - mx[s]) + exp2a(c[7] - mx[s]);
      float e4 = exp2a(c[8] - mx[s]) + exp2a(c[9] - mx[s]);
      float e5 = exp2a(c[10] - mx[s]) + exp2a(c[11] - mx[s]);
      float e6 = exp2a(c[12] - mx[s]) + exp2a(c[13] - mx[s]);
      float e7 = exp2a(c[14] - mx[s]) + exp2a(c[15] - mx[s]);
      sm[s] += ((e0 + e1) + (e2 + e3)) + ((e4 + e5) + (e6 + e7));
    }
  }
#pragma unroll
  for (int s = 0; s < 2; ++s) {
    float omx = __shfl_xor(mx[s], 32);
    float osm = __shfl_xor(sm[s], 32);
    float nm = fmaxf(mx[s], omx);
    sm[s] = sm[s] * exp2a(mx[s] - nm) + osm * exp2a(omx - nm);
    mx[s] = nm;
  }
  __shared__ float smx[4][2][32], ssm[4][2][32];
  if (lane < 32) {
#pragma unroll
    for (int s = 0; s < 2; ++s) {
      smx[w][s][lc] = mx[s];
      ssm[w][s][lc] = sm[s];
    }
  }
  __syncthreads();
  if (tid < 64) {
    const int s = tid >> 5, col = tid & 31;
    float M = fmaxf(fmaxf(smx[0][s][col], smx[1][s][col]),
                    fmaxf(smx[2][s][col], smx[3][s][col]));
    float Ssum = ssm[0][s][col] * exp2a(smx[0][s][col] - M) +
                 ssm[1][s][col] * exp2a(smx[1][s][col] - M) +
                 ssm[2][s][col] * exp2a(smx[2][s][col] - M) +
                 ssm[3][s][col] * exp2a(smx[3][s][col] - M);
    const size_t o = (size_t)(ms * 8 + bbr) * NN + n0 + s * 32 + col;
    pmx[o] = M;
    psm[o] = Ssum;
  }
}

// ---------------------------------------------------------------- pass B
// (R12/R13-proven, verbatim.) FUSED reduceA prologue; ns-split; 64-m tile.
__global__ __launch_bounds__(TPB) void passB_kernel(
    const ushortT* __restrict__ Ehl, const ushortT* __restrict__ Ept,
    const float* __restrict__ pmx, const float* __restrict__ psm,
    float* __restrict__ pb) {
  const int bid = blockIdx.x;
  const int bbr = bid & 7;
  const int ns = (bid >> 3) & 1;
  const int m0 = (bid >> 4) * 64;
  const int tid = threadIdx.x;
  const int w = tid >> 6, lane = tid & 63;
  const int lr = lane & 15, g = lane >> 4;
  const ushortT* Eb = Ehl + (size_t)bbr * NN * 32;
  const ushortT* Tb = Ept + (size_t)bbr * 16 * NN;
  __shared__ float lsb[2048];
  __shared__ float red[4][4][16][17];
  for (int i = tid; i < 2048; i += TPB) {
    const size_t base = (size_t)bbr * NN + ns * 2048 + i;
    float m0v = pmx[base], m1v = pmx[32768 + base];
    float s0v = psm[base], s1v = psm[32768 + base];
    float M = fmaxf(m0v, m1v);
    float Ssum = s0v * exp2a(m0v - M) + s1v * exp2a(m1v - M);
    lsb[i] = -(M + log2f(fmaxf(Ssum, 1e-38f)));
  }
  __syncthreads();

  const short8v zero8 = {0, 0, 0, 0, 0, 0, 0, 0};
  short8v b1[4], b2[4];
#pragma unroll
  for (int s = 0; s < 4; ++s) {
    const ushortT* rp = Eb + (size_t)(m0 + s * 16 + lr) * 32;
    b1[s] = *(const short8v*)(rp + (g & 1) * 8);
    b2[s] = zero8;
    if (g < 2) b2[s] = *(const short8v*)(rp + 16 + g * 8);
  }
  f32x4 acc[4] = {{0.f, 0.f, 0.f, 0.f}, {0.f, 0.f, 0.f, 0.f},
                  {0.f, 0.f, 0.f, 0.f}, {0.f, 0.f, 0.f, 0.f}};
  const ushortT* ap = Eb + (size_t)(ns * 2048 + w * 512 + lr) * 32 + g * 8;
  const ushortT* vp = Tb + (size_t)lr * NN + ns * 2048 + w * 512 + g * 8;
  const float* lp = lsb + w * 512 + g * 4;
#pragma unroll 2
  for (int ch = 0; ch < 16; ++ch) {
    short8v a0 = *(const short8v*)ap;
    short8v a1 = *(const short8v*)(ap + 16 * 32);
    short8v ae = *(const short8v*)vp;
    f32x4 sd0 = *(const f32x4*)lp;          // -lse for rows nb+g*4..+3
    f32x4 sd1 = *(const f32x4*)(lp + 16);   // -lse for rows nb+16+g*4..+3
    ap += 32 * 32; vp += 32; lp += 32;
#pragma unroll
    for (int s = 0; s < 4; ++s) {
      f32x4 c0 = __builtin_amdgcn_mfma_f32_16x16x32_bf16(a0, b1[s], sd0, 0, 0, 0);
      c0 = __builtin_amdgcn_mfma_f32_16x16x32_bf16(a0, b2[s], c0, 0, 0, 0);
      f32x4 c1 = __builtin_amdgcn_mfma_f32_16x16x32_bf16(a1, b1[s], sd1, 0, 0, 0);
      c1 = __builtin_amdgcn_mfma_f32_16x16x32_bf16(a1, b2[s], c1, 0, 0, 0);
      float p0 = exp2a(c0[0]), p1 = exp2a(c0[1]);
      float p2 = exp2a(c0[2]), p3 = exp2a(c0[3]);
      float q0 = exp2a(c1[0]), q1 = exp2a(c1[1]);
      float q2 = exp2a(c1[2]), q3 = exp2a(c1[3]);
      unsigned int u0, u1, u2, u3;
      asm("v_cvt_pk_bf16_f32 %0, %1, %2" : "=v"(u0) : "v"(p0), "v"(p1));
      asm("v_cvt_pk_bf16_f32 %0, %1, %2" : "=v"(u1) : "v"(p2), "v"(p3));
      asm("v_cvt_pk_bf16_f32 %0, %1, %2" : "=v"(u2) : "v"(q0), "v"(q1));
      asm("v_cvt_pk_bf16_f32 %0, %1, %2" : "=v"(u3) : "v"(q2), "v"(q3));
      const uint4 uv = make_uint4(u0, u1, u2, u3);
      const short8v pf = __builtin_bit_cast(short8v, uv);
      acc[s] = __builtin_amdgcn_mfma_f32_16x16x32_bf16(ae, pf, acc[s], 0, 0, 0);
    }
  }
#pragma unroll
  for (int s = 0; s < 4; ++s)
#pragma unroll
    for (int r = 0; r < 4; ++r) red[w][s][g * 4 + r][lr] = acc[s][r];
  __syncthreads();
  for (int o = tid; o < 1024; o += TPB) {
    const int s = o >> 8, l = (o >> 4) & 15, mm = o & 15;
    float v = red[0][s][l][mm] + red[1][s][l][mm] +
              red[2][s][l][mm] + red[3][s][l][mm];
    pb[((size_t)(ns * 8 + bbr) * 16 + l) * NN + m0 + s * 16 + mm] = v;
  }
}

// ---------------------------------------------------------------- reduce B
// (R13-proven, verbatim.)
__global__ __launch_bounds__(TPB) void reduceB_kernel(
    const float* __restrict__ pb, ushortT* __restrict__ EaT) {
  const int gidx = blockIdx.x * TPB + threadIdx.x;   // 0..131071
  const int r = gidx >> 10;                          // bbr*16 + l
  const int j4 = gidx & 1023;
  const float4 p0 = *(const float4*)(pb + (size_t)r * NN + j4 * 4);
  const float4 p1 = *(const float4*)(pb + (size_t)(128 + r) * NN + j4 * 4);
  const float v0 = p0.x + p1.x, v1 = p0.y + p1.y;
  const float v2 = p0.z + p1.z, v3 = p0.w + p1.w;
  const int bbr = r >> 4, l = r & 15;
  unsigned int ue, uo;
  asm("v_cvt_pk_bf16_f32 %0, %1, %2" : "=v"(ue) : "v"(v0), "v"(v2));
  asm("v_cvt_pk_bf16_f32 %0, %1, %2" : "=v"(uo) : "v"(v1), "v"(v3));
  *(unsigned int*)(EaT + ((size_t)(bbr * 2 + 0) * 16 + l) * KK + j4 * 2) = ue;
  *(unsigned int*)(EaT + ((size_t)(bbr * 2 + 1) * 16 + l) * KK + j4 * 2) = uo;
}

// ---------------------------------------------------------------- M-mix (MFMA), k-split x4 -> bf16 partials
// (R13-proven body; ONLY change: pmm stored as bf16 instead of f32.)
__global__ __launch_bounds__(TPB) void mmix_kernel(
    const ushortT* __restrict__ EaT,
    const float* __restrict__ W2x, const float* __restrict__ W2s,
    ushortT* __restrict__ pmm) {
  const int jt = blockIdx.x;   // 0..127
  const int br = blockIdx.y;   // 0..1
  const int ks = blockIdx.z;   // 0..3 (512-row K slice)
  const float* W2 = br ? W2s : W2x;
  const int j0 = jt * 16;
  const int kb = ks * 512;
  const int tid = threadIdx.x;
  const int w = tid >> 6, lane = tid & 63;
  const int b = w;
  const int lj = tid & 15, kp0 = tid >> 4;
  const int fl = lane & 15, g = lane >> 4;
  __shared__ ushortT bpan[2][16][72];

  const size_t rb0 = ((size_t)(br * 4 + b) * 2 + 0) * 16;
  const size_t rb1 = ((size_t)(br * 4 + b) * 2 + 1) * 16;

  f32x4 acc0 = {0.f, 0.f, 0.f, 0.f};
  f32x4 acc1 = {0.f, 0.f, 0.f, 0.f};

  float r0, r1, r2, r3;
  r0 = W2[(size_t)(kb + 2 * kp0)      * KK + j0 + lj];
  r1 = W2[(size_t)(kb + 2 * kp0 + 1)  * KK + j0 + lj];
  r2 = W2[(size_t)(kb + 2 * kp0 + 32) * KK + j0 + lj];
  r3 = W2[(size_t)(kb + 2 * kp0 + 33) * KK + j0 + lj];

  for (int c = 0; c < 8; ++c) {
    const int cur = c & 1;
    unsigned int u0, u1;
    asm("v_cvt_pk_bf16_f32 %0, %1, %2" : "=v"(u0) : "v"(r0), "v"(r1));
    asm("v_cvt_pk_bf16_f32 %0, %1, %2" : "=v"(u1) : "v"(r2), "v"(r3));
    *(unsigned int*)(&bpan[cur][lj][kp0 * 2]) = u0;
    *(unsigned int*)(&bpan[cur][lj][(kp0 + 16) * 2]) = u1;
    __syncthreads();
    if (c < 7) {
      const int kc = kb + (c + 1) * 64;
      r0 = W2[(size_t)(kc + 2 * kp0)      * KK + j0 + lj];
      r1 = W2[(size_t)(kc + 2 * kp0 + 1)  * KK + j0 + lj];
      r2 = W2[(size_t)(kc + 2 * kp0 + 32) * KK + j0 + lj];
      r3 = W2[(size_t)(kc + 2 * kp0 + 33) * KK + j0 + lj];
    }
#pragma unroll
    for (int s = 0; s < 2; ++s) {
      const int k = kb + c * 64 + s * 32 + g * 8;
      short8v bf = *(const short8v*)(&bpan[cur][fl][s * 32 + g * 8]);
      short8v a0 = *(const short8v*)(EaT + (rb0 + fl) * (size_t)KK + k);
      short8v a1 = *(const short8v*)(EaT + (rb1 + fl) * (size_t)KK + k);
      acc0 = __builtin_amdgcn_mfma_f32_16x16x32_bf16(a0, bf, acc0, 0, 0, 0);
      acc1 = __builtin_amdgcn_mfma_f32_16x16x32_bf16(a1, bf, acc1, 0, 0, 0);
    }
    __syncthreads();
  }

  const int j = j0 + fl;
#pragma unroll
  for (int r = 0; r < 4; ++r) {
    const int l = g * 4 + r;
    const size_t base = ((size_t)(ks * 2 + br) * 4 + b) * 2;
    pmm[((base + 0) * 16 + l) * (size_t)KK + j] = f2bf(acc0[r]);
    pmm[((base + 1) * 16 + l) * (size_t)KK + j] = f2bf(acc1[r]);
  }
}

// ---------------------------------------------------------------- 3x3 SAME conv, H=2048 W=2
// (R13-proven body; ONLY change: pmm partials read as bf16.)
__global__ __launch_bounds__(TPB) void conv_kernel(
    const ushortT* __restrict__ pmm,
    const float* __restrict__ X, const float* __restrict__ S,
    const float* __restrict__ Wx, const float* __restrict__ Bx,
    const float* __restrict__ Ws, const float* __restrict__ Bs,
    float* __restrict__ out) {
  const int kt = blockIdx.x;   // 0..63
  const int b = blockIdx.y;
  const int br = blockIdx.z;
  const float* Wt = br ? Ws : Wx;
  const float* Bi = br ? Bs : Bx;
  const float* Inp = br ? S : X;
  __shared__ float inT[32 * 34 * 2];     // [cin][34][2] halo rows
  __shared__ float wts[32 * 289];
  const int tid = threadIdx.x;
  const int k0 = kt * 32;

  for (int f = tid; f < 32 * 288; f += TPB) {
    const int c = f / 288, rem = f % 288;
    wts[c * 289 + rem] = Wt[f];
  }
  for (int f = tid; f < 32 * 34 * 2; f += TPB) {
    const int cin = f / 68, rem = f % 68;
    const int kk = rem >> 1, t = rem & 1;
    const int j = k0 - 1 + kk;
    float v = 0.f;
    if (j >= 0 && j < KK) {
      const int l = cin & 15;
      const float inv = Inp[(size_t)(b * 16 + l) * NN + 2 * j + t];
      if (cin < 16) {
        float sum = 0.f;
#pragma unroll
        for (int ks = 0; ks < 4; ++ks)
          sum += bf2f(pmm[((((size_t)(ks * 2 + br) * 4 + b) * 2 + t) * 16 + l) *
                              (size_t)KK + j]);
        if (br == 0) {
          v = sum * inv;
        } else {
          const float pe = t ? cosf((float)j) : sinf((float)j);
          v = fmaf(sum, inv, pe);
        }
      } else {
        if (br == 0) {
          v = inv;
        } else {
          const float pe = t ? cosf((float)j) : sinf((float)j);
          v = inv + pe;
        }
      }
    }
    inT[f] = v;
  }
  __syncthreads();

  const int c = tid >> 3, sub = tid & 7;
  const float bias = Bi[c];
  float acc0[4], acc1[4];
#pragma unroll
  for (int i = 0; i < 4; ++i) { acc0[i] = bias; acc1[i] = bias; }

  for (int cin = 0; cin < 32; ++cin) {
    const float* wp = wts + c * 289 + cin * 9;
    const float w00 = wp[0], w01 = wp[1], w02 = wp[2];
    const float w10 = wp[3], w11 = wp[4], w12 = wp[5];
    const float w20 = wp[6], w21 = wp[7], w22 = wp[8];
    const float* ip = inT + cin * 68;
#pragma unroll
    for (int i = 0; i < 4; ++i) {
      const int kl = sub + 8 * i;
      const float* q = ip + kl * 2;
      const float i00 = q[0], i01 = q[1];
      const float i10 = q[2], i11 = q[3];
      const float i20 = q[4], i21 = q[5];
      acc0[i] = fmaf(i00, w01, acc0[i]); acc0[i] = fmaf(i01, w02, acc0[i]);
      acc0[i] = fmaf(i10, w11, acc0[i]); acc0[i] = fmaf(i11, w12, acc0[i]);
      acc0[i] = fmaf(i20, w21, acc0[i]); acc0[i] = fmaf(i21, w22, acc0[i]);
      acc1[i] = fmaf(i00, w00, acc1[i]); acc1[i] = fmaf(i01, w01, acc1[i]);
      acc1[i] = fmaf(i10, w10, acc1[i]); acc1[i] = fmaf(i11, w11, acc1[i]);
      acc1[i] = fmaf(i20, w20, acc1[i]); acc1[i] = fmaf(i21, w21, acc1[i]);
    }
  }
#pragma unroll
  for (int i = 0; i < 4; ++i) {
    const int k = k0 + sub + 8 * i;
    const size_t o = ((size_t)(b * 64 + br * 32 + c) * KK + k) * 2;
    out[o] = acc0[i];
    out[o + 1] = acc1[i];
  }
}

// ---------------------------------------------------------------- launch
extern "C" void kernel_launch(void* const* d_in, const int* in_sizes, int n_in,
                              void* d_out, int out_size, void* d_ws, size_t ws_size,
                              hipStream_t stream) {
  (void)in_sizes; (void)n_in; (void)out_size; (void)ws_size;
  const float* X   = (const float*)d_in[0];
  const float* S   = (const float*)d_in[1];
  const float* W1x = (const float*)d_in[2];
  const float* W1s = (const float*)d_in[3];
  const float* W2x = (const float*)d_in[4];
  const float* W2s = (const float*)d_in[5];
  const float* Cwx = (const float*)d_in[6];
  const float* Cbx = (const float*)d_in[7];
  const float* Cws = (const float*)d_in[8];
  const float* Cbs = (const float*)d_in[9];
  float* out = (float*)d_out;
  float* ws = (float*)d_ws;

  ushortT* Ehl = (ushortT*)(ws + OFF_EHL);
  ushortT* Ept = (ushortT*)(ws + OFF_ET);
  ushortT* EaT = (ushortT*)(ws + OFF_EAT);
  float*   pb  = ws + OFF_PB;
  float*   pmx = ws + OFF_PMX;
  float*   psm = ws + OFF_PSM;
  ushortT* pmm = (ushortT*)(ws + OFF_PMM);

  hipLaunchKernelGGL(prep_kernel, dim3(16, NBATCH, 2), dim3(TPB), 0, stream,
                     X, S, W1x, W1s, Ehl, Ept);
  hipLaunchKernelGGL(passA_kernel, dim3(1024), dim3(TPB), 0, stream,
                     Ehl, pmx, psm);
  hipLaunchKernelGGL(passB_kernel, dim3(1024), dim3(TPB), 0, stream,
                     Ehl, Ept, pmx, psm, pb);
  hipLaunchKernelGGL(reduceB_kernel, dim3(512), dim3(TPB), 0, stream,
                     pb, EaT);
  hipLaunchKernelGGL(mmix_kernel, dim3(128, 2, 4), dim3(TPB), 0, stream,
                     EaT, W2x, W2s, pmm);
  hipLaunchKernelGGL(conv_kernel, dim3(64, NBATCH, 2), dim3(TPB), 0, stream,
                     pmm, X, S, Cwx, Cbx, Cws, Cbs, out);
}

// Round 19
// 106.826 us; speedup vs baseline: 1.0547x; 1.0055x over previous
//
#include <hip/hip_runtime.h>
#include <math.h>

#define TPB 256

static constexpr int LL = 16;
static constexpr int KK = 2048;
static constexpr int NBATCH = 4;
static constexpr int NN = 4096;        // K*B
static constexpr int BBR = 8;          // (branch, batch) combos

// workspace layout in float slots (ws is ~268MB)
static constexpr size_t OFF_EHL = 0;          // 8*4096*32 bf16 = 524288 f
static constexpr size_t OFF_ET  = 524288;     // 8*16*4096 bf16 = 262144 f (n-permuted)
static constexpr size_t OFF_EAT = 819200;     // 8*2*16*2048 bf16 = 262144 f
static constexpr size_t OFF_PB  = 2129920;    // 2*8*16*4096 bf16 (region reused)
static constexpr size_t OFF_PMX = 3178496;    // 2*8*4096 f32 = 65536 f
static constexpr size_t OFF_PSM = 3244032;    // 65536 f
static constexpr size_t OFF_PMM = 3309568;    // 4ks*2br*4b*2t*16l*2048j bf16
typedef unsigned short ushortT;
typedef __attribute__((ext_vector_type(8))) short short8v;
typedef __attribute__((ext_vector_type(4))) float f32x4;
typedef __attribute__((ext_vector_type(16))) float f32x16;

__device__ __forceinline__ ushortT f2bf(float x) {
  union { float f; unsigned int u; } c; c.f = x;
  unsigned int u = c.u;
  return (ushortT)((u + 0x7FFFu + ((u >> 16) & 1u)) >> 16);
}
__device__ __forceinline__ float bf2f(ushortT h) {
  union { unsigned int u; float f; } c; c.u = ((unsigned int)h) << 16;
  return c.f;
}
__device__ __forceinline__ float exp2a(float x) {
  float r; asm("v_exp_f32 %0, %1" : "=v"(r) : "v"(x)); return r;
}

// ---------------------------------------------------------------- prep
// (R8-proven, verbatim.) One branch per blockIdx.z.
__global__ __launch_bounds__(TPB) void prep_kernel(
    const float* __restrict__ X, const float* __restrict__ S,
    const float* __restrict__ W1x, const float* __restrict__ W1s,
    ushortT* __restrict__ Ehl, ushortT* __restrict__ Ept) {
  __shared__ float wsh[256];
  __shared__ ushortT tl[16][272];
  const int tid = threadIdx.x;
  const int br = blockIdx.z;
  wsh[tid] = br ? W1s[tid] : W1x[tid];
  __syncthreads();
  const int n0 = blockIdx.x * 256;
  const int b = blockIdx.y;
  const int n = n0 + tid;
  const float SC = 1.2011224087f;  // sqrt(log2(e))
  const int wq = tid & 31;
  const int slot = (wq < 16) ? ((wq >> 2) * 8 + (wq & 3))
                             : (((wq - 16) >> 2) * 8 + 4 + (wq & 3));
  const int ptid = (tid & ~31) | slot;
  const float* In = br ? X : S;     // Xe uses S, Se uses X (cross-wired)

  float in[16];
#pragma unroll
  for (int l = 0; l < 16; ++l)
    in[l] = In[(size_t)(b * 16 + l) * NN + n];
  float e[16];
#pragma unroll
  for (int m = 0; m < 16; ++m) {
    float a0 = 0.f;
#pragma unroll
    for (int l = 0; l < 16; ++l) a0 = fmaf(in[l], wsh[l * 16 + m], a0);
    e[m] = a0;
  }
  const int bbr = br * 4 + b;
  unsigned int rw[16];
#pragma unroll
  for (int q = 0; q < 16; ++q) rw[q] = 0;
#pragma unroll
  for (int k = 0; k < 16; ++k) {
    const float vs = e[k] * SC;
    ushortT h = f2bf(vs);
    ushortT lo = f2bf(vs - bf2f(h));
    rw[k >> 1] |= ((unsigned int)h) << (16 * (k & 1));
    rw[8 + (k >> 1)] |= ((unsigned int)lo) << (16 * (k & 1));
    tl[k][ptid] = f2bf(e[k]);           // unscaled hi for PV operand
  }
  uint4* dst = (uint4*)(Ehl + ((size_t)bbr * NN + n) * 32);
  dst[0] = make_uint4(rw[0], rw[1], rw[2], rw[3]);
  dst[1] = make_uint4(rw[4], rw[5], rw[6], rw[7]);
  dst[2] = make_uint4(rw[8], rw[9], rw[10], rw[11]);
  dst[3] = make_uint4(rw[12], rw[13], rw[14], rw[15]);
  __syncthreads();
  {
    const int r = tid >> 4, c0 = (tid & 15) * 16;
    const uint4* src = (const uint4*)(&tl[r][c0]);
    uint4* d2 = (uint4*)(Ept + ((size_t)bbr * 16 + r) * NN + n0 + c0);
    d2[0] = src[0];
    d2[1] = src[1];
  }
}

// ---------------------------------------------------------------- pass A (32x32x16 MFMA)
// (R13-proven, verbatim.)
__global__ __launch_bounds__(TPB) void passA_kernel(
    const ushortT* __restrict__ Ehl, float* __restrict__ pmx,
    float* __restrict__ psm) {
  const int bid = blockIdx.x;
  const int bbr = bid & 7;
  const int ms = (bid >> 3) & 1;
  const int n0 = (bid >> 4) * 64;
  const int tid = threadIdx.x;
  const int w = tid >> 6, lane = tid & 63;
  const int lc = lane & 31;
  const int koff = (lane >> 5) * 8;      // k-slot offset for A/B frags
  const ushortT* Eb = Ehl + (size_t)bbr * NN * 32;

  short8v bh[2], bl[2];
#pragma unroll
  for (int s = 0; s < 2; ++s) {
    const ushortT* rp = Eb + (size_t)(n0 + s * 32 + lc) * 32;
    bh[s] = *(const short8v*)(rp + koff);
    bl[s] = *(const short8v*)(rp + 16 + koff);
  }
  float mx[2] = {-INFINITY, -INFINITY};
  float sm[2] = {0.f, 0.f};
  const f32x16 z16 = {0.f, 0.f, 0.f, 0.f, 0.f, 0.f, 0.f, 0.f,
                      0.f, 0.f, 0.f, 0.f, 0.f, 0.f, 0.f, 0.f};
  const ushortT* ap = Eb + (size_t)(ms * 2048 + w * 512 + lc) * 32;
  for (int ch = 0; ch < 16; ++ch) {
    short8v ah = *(const short8v*)(ap + koff);
    short8v al = *(const short8v*)(ap + 16 + koff);
    ap += 32 * 32;
#pragma unroll
    for (int s = 0; s < 2; ++s) {
      f32x16 c = __builtin_amdgcn_mfma_f32_32x32x16_bf16(ah, bh[s], z16, 0, 0, 0);
      c = __builtin_amdgcn_mfma_f32_32x32x16_bf16(al, bh[s], c, 0, 0, 0);
      c = __builtin_amdgcn_mfma_f32_32x32x16_bf16(ah, bl[s], c, 0, 0, 0);
      float t0 = fmaxf(fmaxf(c[0], c[1]), fmaxf(c[2], c[3]));
      float t1 = fmaxf(fmaxf(c[4], c[5]), fmaxf(c[6], c[7]));
      float t2 = fmaxf(fmaxf(c[8], c[9]), fmaxf(c[10], c[11]));
      float t3 = fmaxf(fmaxf(c[12], c[13]), fmaxf(c[14], c[15]));
      float tm = fmaxf(fmaxf(t0, t1), fmaxf(t2, t3));
      if (tm > mx[s] + 30.f) {            // deferred rescale (rare)
        sm[s] *= exp2a(mx[s] - tm);
        mx[s] = tm;
      }
      float e0 = exp2a(c[0] - mx[s]) + exp2a(c[1] - mx[s]);
      float e1 = exp2a(c[2] - mx[s]) + exp2a(c[3] - mx[s]);
      float e2 = exp2a(c[4] - mx[s]) + exp2a(c[5] - mx[s]);
      float e3 = exp2a(c[6] - mx[s]) + exp2a(c[7] - mx[s]);
      float e4 = exp2a(c[8] - mx[s]) + exp2a(c[9] - mx[s]);
      float e5 = exp2a(c[10] - mx[s]) + exp2a(c[11] - mx[s]);
      float e6 = exp2a(c[12] - mx[s]) + exp2a(c[13] - mx[s]);
      float e7 = exp2a(c[14] - mx[s]) + exp2a(c[15] - mx[s]);
      sm[s] += ((e0 + e1) + (e2 + e3)) + ((e4 + e5) + (e6 + e7));
    }
  }
#pragma unroll
  for (int s = 0; s < 2; ++s) {
    float omx = __shfl_xor(mx[s], 32);
    float osm = __shfl_xor(sm[s], 32);
    float nm = fmaxf(mx[s], omx);
    sm[s] = sm[s] * exp2a(mx[s] - nm) + osm * exp2a(omx - nm);
    mx[s] = nm;
  }
  __shared__ float smx[4][2][32], ssm[4][2][32];
  if (lane < 32) {
#pragma unroll
    for (int s = 0; s < 2; ++s) {
      smx[w][s][lc] = mx[s];
      ssm[w][s][lc] = sm[s];
    }
  }
  __syncthreads();
  if (tid < 64) {
    const int s = tid >> 5, col = tid & 31;
    float M = fmaxf(fmaxf(smx[0][s][col], smx[1][s][col]),
                    fmaxf(smx[2][s][col], smx[3][s][col]));
    float Ssum = ssm[0][s][col] * exp2a(smx[0][s][col] - M) +
                 ssm[1][s][col] * exp2a(smx[1][s][col] - M) +
                 ssm[2][s][col] * exp2a(smx[2][s][col] - M) +
                 ssm[3][s][col] * exp2a(smx[3][s][col] - M);
    const size_t o = (size_t)(ms * 8 + bbr) * NN + n0 + s * 32 + col;
    pmx[o] = M;
    psm[o] = Ssum;
  }
}

// ---------------------------------------------------------------- pass B
// (R13-proven body; ONLY change: pb partials stored as bf16.)
__global__ __launch_bounds__(TPB) void passB_kernel(
    const ushortT* __restrict__ Ehl, const ushortT* __restrict__ Ept,
    const float* __restrict__ pmx, const float* __restrict__ psm,
    ushortT* __restrict__ pb) {
  const int bid = blockIdx.x;
  const int bbr = bid & 7;
  const int ns = (bid >> 3) & 1;
  const int m0 = (bid >> 4) * 64;
  const int tid = threadIdx.x;
  const int w = tid >> 6, lane = tid & 63;
  const int lr = lane & 15, g = lane >> 4;
  const ushortT* Eb = Ehl + (size_t)bbr * NN * 32;
  const ushortT* Tb = Ept + (size_t)bbr * 16 * NN;
  __shared__ float lsb[2048];
  __shared__ float red[4][4][16][17];
  for (int i = tid; i < 2048; i += TPB) {
    const size_t base = (size_t)bbr * NN + ns * 2048 + i;
    float m0v = pmx[base], m1v = pmx[32768 + base];
    float s0v = psm[base], s1v = psm[32768 + base];
    float M = fmaxf(m0v, m1v);
    float Ssum = s0v * exp2a(m0v - M) + s1v * exp2a(m1v - M);
    lsb[i] = -(M + log2f(fmaxf(Ssum, 1e-38f)));
  }
  __syncthreads();

  const short8v zero8 = {0, 0, 0, 0, 0, 0, 0, 0};
  short8v b1[4], b2[4];
#pragma unroll
  for (int s = 0; s < 4; ++s) {
    const ushortT* rp = Eb + (size_t)(m0 + s * 16 + lr) * 32;
    b1[s] = *(const short8v*)(rp + (g & 1) * 8);
    b2[s] = zero8;
    if (g < 2) b2[s] = *(const short8v*)(rp + 16 + g * 8);
  }
  f32x4 acc[4] = {{0.f, 0.f, 0.f, 0.f}, {0.f, 0.f, 0.f, 0.f},
                  {0.f, 0.f, 0.f, 0.f}, {0.f, 0.f, 0.f, 0.f}};
  const ushortT* ap = Eb + (size_t)(ns * 2048 + w * 512 + lr) * 32 + g * 8;
  const ushortT* vp = Tb + (size_t)lr * NN + ns * 2048 + w * 512 + g * 8;
  const float* lp = lsb + w * 512 + g * 4;
#pragma unroll 2
  for (int ch = 0; ch < 16; ++ch) {
    short8v a0 = *(const short8v*)ap;
    short8v a1 = *(const short8v*)(ap + 16 * 32);
    short8v ae = *(const short8v*)vp;
    f32x4 sd0 = *(const f32x4*)lp;          // -lse for rows nb+g*4..+3
    f32x4 sd1 = *(const f32x4*)(lp + 16);   // -lse for rows nb+16+g*4..+3
    ap += 32 * 32; vp += 32; lp += 32;
#pragma unroll
    for (int s = 0; s < 4; ++s) {
      f32x4 c0 = __builtin_amdgcn_mfma_f32_16x16x32_bf16(a0, b1[s], sd0, 0, 0, 0);
      c0 = __builtin_amdgcn_mfma_f32_16x16x32_bf16(a0, b2[s], c0, 0, 0, 0);
      f32x4 c1 = __builtin_amdgcn_mfma_f32_16x16x32_bf16(a1, b1[s], sd1, 0, 0, 0);
      c1 = __builtin_amdgcn_mfma_f32_16x16x32_bf16(a1, b2[s], c1, 0, 0, 0);
      float p0 = exp2a(c0[0]), p1 = exp2a(c0[1]);
      float p2 = exp2a(c0[2]), p3 = exp2a(c0[3]);
      float q0 = exp2a(c1[0]), q1 = exp2a(c1[1]);
      float q2 = exp2a(c1[2]), q3 = exp2a(c1[3]);
      unsigned int u0, u1, u2, u3;
      asm("v_cvt_pk_bf16_f32 %0, %1, %2" : "=v"(u0) : "v"(p0), "v"(p1));
      asm("v_cvt_pk_bf16_f32 %0, %1, %2" : "=v"(u1) : "v"(p2), "v"(p3));
      asm("v_cvt_pk_bf16_f32 %0, %1, %2" : "=v"(u2) : "v"(q0), "v"(q1));
      asm("v_cvt_pk_bf16_f32 %0, %1, %2" : "=v"(u3) : "v"(q2), "v"(q3));
      const uint4 uv = make_uint4(u0, u1, u2, u3);
      const short8v pf = __builtin_bit_cast(short8v, uv);
      acc[s] = __builtin_amdgcn_mfma_f32_16x16x32_bf16(ae, pf, acc[s], 0, 0, 0);
    }
  }
#pragma unroll
  for (int s = 0; s < 4; ++s)
#pragma unroll
    for (int r = 0; r < 4; ++r) red[w][s][g * 4 + r][lr] = acc[s][r];
  __syncthreads();
  for (int o = tid; o < 1024; o += TPB) {
    const int s = o >> 8, l = (o >> 4) & 15, mm = o & 15;
    float v = red[0][s][l][mm] + red[1][s][l][mm] +
              red[2][s][l][mm] + red[3][s][l][mm];
    pb[((size_t)(ns * 8 + bbr) * 16 + l) * NN + m0 + s * 16 + mm] = f2bf(v);
  }
}

// ---------------------------------------------------------------- reduce B
// (R13-proven body; ONLY change: pb partials read as bf16.)
__global__ __launch_bounds__(TPB) void reduceB_kernel(
    const ushortT* __restrict__ pb, ushortT* __restrict__ EaT) {
  const int gidx = blockIdx.x * TPB + threadIdx.x;   // 0..131071
  const int r = gidx >> 10;                          // bbr*16 + l
  const int j4 = gidx & 1023;
  const ushortT* p0p = pb + (size_t)r * NN + j4 * 4;
  const ushortT* p1p = pb + (size_t)(128 + r) * NN + j4 * 4;
  const float v0 = bf2f(p0p[0]) + bf2f(p1p[0]);
  const float v1 = bf2f(p0p[1]) + bf2f(p1p[1]);
  const float v2 = bf2f(p0p[2]) + bf2f(p1p[2]);
  const float v3 = bf2f(p0p[3]) + bf2f(p1p[3]);
  const int bbr = r >> 4, l = r & 15;
  unsigned int ue, uo;
  asm("v_cvt_pk_bf16_f32 %0, %1, %2" : "=v"(ue) : "v"(v0), "v"(v2));
  asm("v_cvt_pk_bf16_f32 %0, %1, %2" : "=v"(uo) : "v"(v1), "v"(v3));
  *(unsigned int*)(EaT + ((size_t)(bbr * 2 + 0) * 16 + l) * KK + j4 * 2) = ue;
  *(unsigned int*)(EaT + ((size_t)(bbr * 2 + 1) * 16 + l) * KK + j4 * 2) = uo;
}

// ---------------------------------------------------------------- M-mix (MFMA), k-split x4 -> bf16 partials
// (R18-proven, verbatim.)
__global__ __launch_bounds__(TPB) void mmix_kernel(
    const ushortT* __restrict__ EaT,
    const float* __restrict__ W2x, const float* __restrict__ W2s,
    ushortT* __restrict__ pmm) {
  const int jt = blockIdx.x;   // 0..127
  const int br = blockIdx.y;   // 0..1
  const int ks = blockIdx.z;   // 0..3 (512-row K slice)
  const float* W2 = br ? W2s : W2x;
  const int j0 = jt * 16;
  const int kb = ks * 512;
  const int tid = threadIdx.x;
  const int w = tid >> 6, lane = tid & 63;
  const int b = w;
  const int lj = tid & 15, kp0 = tid >> 4;
  const int fl = lane & 15, g = lane >> 4;
  __shared__ ushortT bpan[2][16][72];

  const size_t rb0 = ((size_t)(br * 4 + b) * 2 + 0) * 16;
  const size_t rb1 = ((size_t)(br * 4 + b) * 2 + 1) * 16;

  f32x4 acc0 = {0.f, 0.f, 0.f, 0.f};
  f32x4 acc1 = {0.f, 0.f, 0.f, 0.f};

  float r0, r1, r2, r3;
  r0 = W2[(size_t)(kb + 2 * kp0)      * KK + j0 + lj];
  r1 = W2[(size_t)(kb + 2 * kp0 + 1)  * KK + j0 + lj];
  r2 = W2[(size_t)(kb + 2 * kp0 + 32) * KK + j0 + lj];
  r3 = W2[(size_t)(kb + 2 * kp0 + 33) * KK + j0 + lj];

  for (int c = 0; c < 8; ++c) {
    const int cur = c & 1;
    unsigned int u0, u1;
    asm("v_cvt_pk_bf16_f32 %0, %1, %2" : "=v"(u0) : "v"(r0), "v"(r1));
    asm("v_cvt_pk_bf16_f32 %0, %1, %2" : "=v"(u1) : "v"(r2), "v"(r3));
    *(unsigned int*)(&bpan[cur][lj][kp0 * 2]) = u0;
    *(unsigned int*)(&bpan[cur][lj][(kp0 + 16) * 2]) = u1;
    __syncthreads();
    if (c < 7) {
      const int kc = kb + (c + 1) * 64;
      r0 = W2[(size_t)(kc + 2 * kp0)      * KK + j0 + lj];
      r1 = W2[(size_t)(kc + 2 * kp0 + 1)  * KK + j0 + lj];
      r2 = W2[(size_t)(kc + 2 * kp0 + 32) * KK + j0 + lj];
      r3 = W2[(size_t)(kc + 2 * kp0 + 33) * KK + j0 + lj];
    }
#pragma unroll
    for (int s = 0; s < 2; ++s) {
      const int k = kb + c * 64 + s * 32 + g * 8;
      short8v bf = *(const short8v*)(&bpan[cur][fl][s * 32 + g * 8]);
      short8v a0 = *(const short8v*)(EaT + (rb0 + fl) * (size_t)KK + k);
      short8v a1 = *(const short8v*)(EaT + (rb1 + fl) * (size_t)KK + k);
      acc0 = __builtin_amdgcn_mfma_f32_16x16x32_bf16(a0, bf, acc0, 0, 0, 0);
      acc1 = __builtin_amdgcn_mfma_f32_16x16x32_bf16(a1, bf, acc1, 0, 0, 0);
    }
    __syncthreads();
  }

  const int j = j0 + fl;
#pragma unroll
  for (int r = 0; r < 4; ++r) {
    const int l = g * 4 + r;
    const size_t base = ((size_t)(ks * 2 + br) * 4 + b) * 2;
    pmm[((base + 0) * 16 + l) * (size_t)KK + j] = f2bf(acc0[r]);
    pmm[((base + 1) * 16 + l) * (size_t)KK + j] = f2bf(acc1[r]);
  }
}

// ---------------------------------------------------------------- 3x3 SAME conv, H=2048 W=2
// (R18-proven, verbatim.) FUSED mergeM; pmm partials read as bf16.
__global__ __launch_bounds__(TPB) void conv_kernel(
    const ushortT* __restrict__ pmm,
    const float* __restrict__ X, const float* __restrict__ S,
    const float* __restrict__ Wx, const float* __restrict__ Bx,
    const float* __restrict__ Ws, const float* __restrict__ Bs,
    float* __restrict__ out) {
  const int kt = blockIdx.x;   // 0..63
  const int b = blockIdx.y;
  const int br = blockIdx.z;
  const float* Wt = br ? Ws : Wx;
  const float* Bi = br ? Bs : Bx;
  const float* Inp = br ? S : X;
  __shared__ float inT[32 * 34 * 2];     // [cin][34][2] halo rows
  __shared__ float wts[32 * 289];
  const int tid = threadIdx.x;
  const int k0 = kt * 32;

  for (int f = tid; f < 32 * 288; f += TPB) {
    const int c = f / 288, rem = f % 288;
    wts[c * 289 + rem] = Wt[f];
  }
  for (int f = tid; f < 32 * 34 * 2; f += TPB) {
    const int cin = f / 68, rem = f % 68;
    const int kk = rem >> 1, t = rem & 1;
    const int j = k0 - 1 + kk;
    float v = 0.f;
    if (j >= 0 && j < KK) {
      const int l = cin & 15;
      const float inv = Inp[(size_t)(b * 16 + l) * NN + 2 * j + t];
      if (cin < 16) {
        float sum = 0.f;
#pragma unroll
        for (int ks = 0; ks < 4; ++ks)
          sum += bf2f(pmm[((((size_t)(ks * 2 + br) * 4 + b) * 2 + t) * 16 + l) *
                              (size_t)KK + j]);
        if (br == 0) {
          v = sum * inv;
        } else {
          const float pe = t ? cosf((float)j) : sinf((float)j);
          v = fmaf(sum, inv, pe);
        }
      } else {
        if (br == 0) {
          v = inv;
        } else {
          const float pe = t ? cosf((float)j) : sinf((float)j);
          v = inv + pe;
        }
      }
    }
    inT[f] = v;
  }
  __syncthreads();

  const int c = tid >> 3, sub = tid & 7;
  const float bias = Bi[c];
  float acc0[4], acc1[4];
#pragma unroll
  for (int i = 0; i < 4; ++i) { acc0[i] = bias; acc1[i] = bias; }

  for (int cin = 0; cin < 32; ++cin) {
    const float* wp = wts + c * 289 + cin * 9;
    const float w00 = wp[0], w01 = wp[1], w02 = wp[2];
    const float w10 = wp[3], w11 = wp[4], w12 = wp[5];
    const float w20 = wp[6], w21 = wp[7], w22 = wp[8];
    const float* ip = inT + cin * 68;
#pragma unroll
    for (int i = 0; i < 4; ++i) {
      const int kl = sub + 8 * i;
      const float* q = ip + kl * 2;
      const float i00 = q[0], i01 = q[1];
      const float i10 = q[2], i11 = q[3];
      const float i20 = q[4], i21 = q[5];
      acc0[i] = fmaf(i00, w01, acc0[i]); acc0[i] = fmaf(i01, w02, acc0[i]);
      acc0[i] = fmaf(i10, w11, acc0[i]); acc0[i] = fmaf(i11, w12, acc0[i]);
      acc0[i] = fmaf(i20, w21, acc0[i]); acc0[i] = fmaf(i21, w22, acc0[i]);
      acc1[i] = fmaf(i00, w00, acc1[i]); acc1[i] = fmaf(i01, w01, acc1[i]);
      acc1[i] = fmaf(i10, w10, acc1[i]); acc1[i] = fmaf(i11, w11, acc1[i]);
      acc1[i] = fmaf(i20, w20, acc1[i]); acc1[i] = fmaf(i21, w21, acc1[i]);
    }
  }
#pragma unroll
  for (int i = 0; i < 4; ++i) {
    const int k = k0 + sub + 8 * i;
    const size_t o = ((size_t)(b * 64 + br * 32 + c) * KK + k) * 2;
    out[o] = acc0[i];
    out[o + 1] = acc1[i];
  }
}

// ---------------------------------------------------------------- launch
extern "C" void kernel_launch(void* const* d_in, const int* in_sizes, int n_in,
                              void* d_out, int out_size, void* d_ws, size_t ws_size,
                              hipStream_t stream) {
  (void)in_sizes; (void)n_in; (void)out_size; (void)ws_size;
  const float* X   = (const float*)d_in[0];
  const float* S   = (const float*)d_in[1];
  const float* W1x = (const float*)d_in[2];
  const float* W1s = (const float*)d_in[3];
  const float* W2x = (const float*)d_in[4];
  const float* W2s = (const float*)d_in[5];
  const float* Cwx = (const float*)d_in[6];
  const float* Cbx = (const float*)d_in[7];
  const float* Cws = (const float*)d_in[8];
  const float* Cbs = (const float*)d_in[9];
  float* out = (float*)d_out;
  float* ws = (float*)d_ws;

  ushortT* Ehl = (ushortT*)(ws + OFF_EHL);
  ushortT* Ept = (ushortT*)(ws + OFF_ET);
  ushortT* EaT = (ushortT*)(ws + OFF_EAT);
  ushortT* pb  = (ushortT*)(ws + OFF_PB);
  float*   pmx = ws + OFF_PMX;
  float*   psm = ws + OFF_PSM;
  ushortT* pmm = (ushortT*)(ws + OFF_PMM);

  hipLaunchKernelGGL(prep_kernel, dim3(16, NBATCH, 2), dim3(TPB), 0, stream,
                     X, S, W1x, W1s, Ehl, Ept);
  hipLaunchKernelGGL(passA_kernel, dim3(1024), dim3(TPB), 0, stream,
                     Ehl, pmx, psm);
  hipLaunchKernelGGL(passB_kernel, dim3(1024), dim3(TPB), 0, stream,
                     Ehl, Ept, pmx, psm, pb);
  hipLaunchKernelGGL(reduceB_kernel, dim3(512), dim3(TPB), 0, stream,
                     pb, EaT);
  hipLaunchKernelGGL(mmix_kernel, dim3(128, 2, 4), dim3(TPB), 0, stream,
                     EaT, W2x, W2s, pmm);
  hipLaunchKernelGGL(conv_kernel, dim3(64, NBATCH, 2), dim3(TPB), 0, stream,
                     pmm, X, S, Cwx, Cbx, Cws, Cbs, out);
}